// Round 1
// baseline (423.817 us; speedup 1.0000x reference)
//
#include <hip/hip_runtime.h>
#include <cstdint>

// ---------------------------------------------------------------------------
// TinyViT block on gfx950. Round 1: correctness-first with bf16 MFMA GEMMs
// (m97 pattern: 128x128 tile, global_load_lds width=16, 16x16x32 bf16 MFMA).
// ---------------------------------------------------------------------------

typedef __bf16 bf16x8 __attribute__((ext_vector_type(8)));
typedef float  f32x4  __attribute__((ext_vector_type(4)));

#define DIM_    384
#define QKVD    1152
#define HIDD    1536
#define NTOK    49
#define NWIN    400
#define MPAD    19712     /* 154*128 */
#define MREAL   19600
#define TOKENS  16384     /* 4*4096 */
#define SCALE_  0.17677669529663689f
#define EPS_    1e-5f

__device__ __forceinline__ void gload_lds16(const void* g, void* l) {
  __builtin_amdgcn_global_load_lds(
      (__attribute__((address_space(1))) void*)g,
      (__attribute__((address_space(3))) void*)l, 16, 0, 0);
}

// ---------------------------------------------------------------------------
// Weight transpose + cast: dst[n*K+k] = bf16(src[k*N+n])   (K x N -> N x K)
// ---------------------------------------------------------------------------
__global__ void transpose_cast(const float* __restrict__ src, __bf16* __restrict__ dst,
                               int K, int N) {
  long id = (long)blockIdx.x * 256 + threadIdx.x;
  if (id >= (long)K * N) return;
  int  k = (int)(id % K);
  long n = id / K;
  dst[n * K + k] = (__bf16)src[(long)k * N + n];
}

// ---------------------------------------------------------------------------
// LN1 + window partition. Block = one padded-window token (19712), 128 thr.
// pad pixels (r>=64 || c>=64) -> ln1_b exactly; rows >= 19600 -> zeros.
// ---------------------------------------------------------------------------
__global__ void ln1_window(const float* __restrict__ x, const float* __restrict__ gam,
                           const float* __restrict__ bet, __bf16* __restrict__ xn) {
  int t   = blockIdx.x;
  int tid = threadIdx.x;
  __bf16* orow = xn + (long)t * DIM_;
  if (t >= MREAL) {
    for (int i = tid; i < DIM_; i += 128) orow[i] = (__bf16)0.f;
    return;
  }
  int win = t / NTOK, tt = t % NTOK;
  int bb = win / 100, rem = win % 100;
  int r = (rem / 10) * 7 + tt / 7;
  int c = (rem % 10) * 7 + tt % 7;
  if (r >= 64 || c >= 64) {
    for (int i = tid; i < DIM_; i += 128) orow[i] = (__bf16)bet[i];
    return;
  }
  const float* xr = x + ((long)bb * 4096 + r * 64 + c) * DIM_;
  float v0 = xr[tid], v1 = xr[tid + 128], v2 = xr[tid + 256];
  float s = v0 + v1 + v2, s2 = v0 * v0 + v1 * v1 + v2 * v2;
  for (int off = 32; off; off >>= 1) { s += __shfl_down(s, off); s2 += __shfl_down(s2, off); }
  __shared__ float red[4];
  if ((tid & 63) == 0) { red[tid >> 6] = s; red[2 + (tid >> 6)] = s2; }
  __syncthreads();
  float S = red[0] + red[1], S2 = red[2] + red[3];
  float m  = S * (1.f / DIM_);
  float rs = rsqrtf(S2 * (1.f / DIM_) - m * m + EPS_);
  orow[tid]       = (__bf16)((v0 - m) * rs * gam[tid]       + bet[tid]);
  orow[tid + 128] = (__bf16)((v1 - m) * rs * gam[tid + 128] + bet[tid + 128]);
  orow[tid + 256] = (__bf16)((v2 - m) * rs * gam[tid + 256] + bet[tid + 256]);
}

// ---------------------------------------------------------------------------
// LN2 (plain, over X2). Block = one token (16384), 128 threads.
// ---------------------------------------------------------------------------
__global__ void ln2_kernel(const float* __restrict__ x2, const float* __restrict__ gam,
                           const float* __restrict__ bet, __bf16* __restrict__ out) {
  long t  = blockIdx.x;
  int tid = threadIdx.x;
  const float* xr = x2 + t * DIM_;
  float v0 = xr[tid], v1 = xr[tid + 128], v2 = xr[tid + 256];
  float s = v0 + v1 + v2, s2 = v0 * v0 + v1 * v1 + v2 * v2;
  for (int off = 32; off; off >>= 1) { s += __shfl_down(s, off); s2 += __shfl_down(s2, off); }
  __shared__ float red[4];
  if ((tid & 63) == 0) { red[tid >> 6] = s; red[2 + (tid >> 6)] = s2; }
  __syncthreads();
  float S = red[0] + red[1], S2 = red[2] + red[3];
  float m  = S * (1.f / DIM_);
  float rs = rsqrtf(S2 * (1.f / DIM_) - m * m + EPS_);
  __bf16* orow = out + t * DIM_;
  orow[tid]       = (__bf16)((v0 - m) * rs * gam[tid]       + bet[tid]);
  orow[tid + 128] = (__bf16)((v1 - m) * rs * gam[tid + 128] + bet[tid + 128]);
  orow[tid + 256] = (__bf16)((v2 - m) * rs * gam[tid + 256] + bet[tid + 256]);
}

// ---------------------------------------------------------------------------
// Windowed attention: one block per (window, head). 400*12 = 4800 blocks.
// qkv is bf16 [MPAD][1152] = [n][h][q32|k32|v32]. Bias computed inline:
// idx = |n/7-m/7|*7 + |n%7-m%7| (derived from BIAS_IDXS construction).
// ---------------------------------------------------------------------------
__global__ __launch_bounds__(256) void attn_kernel(const __bf16* __restrict__ qkv,
                                                   const float* __restrict__ attn_bias,
                                                   __bf16* __restrict__ o) {
  int blk = blockIdx.x;
  int win = blk / 12, h = blk % 12;
  __shared__ float qs[NTOK][33], ks[NTOK][33], vs[NTOK][33];
  __shared__ float sc[NTOK][50];
  __shared__ float rmax[NTOK], rsum[NTOK], sb[NTOK];
  int tid = threadIdx.x;

  const __bf16* base = qkv + (long)win * NTOK * QKVD + h * 96;
  for (int i = tid; i < NTOK * 96; i += 256) {
    int n = i / 96, j = i % 96;
    float val = (float)base[(long)n * QKVD + j];
    int d = j & 31;
    if (j < 32)      qs[n][d] = val;
    else if (j < 64) ks[n][d] = val;
    else             vs[n][d] = val;
  }
  if (tid < NTOK) sb[tid] = attn_bias[h * NTOK + tid];
  __syncthreads();

  for (int p = tid; p < NTOK * NTOK; p += 256) {
    int n = p / NTOK, m = p % NTOK;
    float acc = 0.f;
    #pragma unroll
    for (int d = 0; d < 32; d++) acc += qs[n][d] * ks[m][d];
    int idx = abs(n / 7 - m / 7) * 7 + abs(n % 7 - m % 7);
    sc[n][m] = acc * SCALE_ + sb[idx];
  }
  __syncthreads();
  if (tid < NTOK) {
    float mx = -1e30f;
    for (int m = 0; m < NTOK; m++) mx = fmaxf(mx, sc[tid][m]);
    rmax[tid] = mx;
  }
  __syncthreads();
  for (int p = tid; p < NTOK * NTOK; p += 256) {
    int n = p / NTOK, m = p % NTOK;
    sc[n][m] = __expf(sc[n][m] - rmax[n]);
  }
  __syncthreads();
  if (tid < NTOK) {
    float s = 0.f;
    for (int m = 0; m < NTOK; m++) s += sc[tid][m];
    rsum[tid] = 1.f / s;
  }
  __syncthreads();
  for (int p = tid; p < NTOK * 32; p += 256) {
    int n = p >> 5, d = p & 31;
    float acc = 0.f;
    #pragma unroll
    for (int m = 0; m < NTOK; m++) acc += sc[n][m] * vs[m][d];
    o[((long)win * NTOK + n) * DIM_ + h * 32 + d] = (__bf16)(acc * rsum[n]);
  }
}

// ---------------------------------------------------------------------------
// Depthwise 3x3 conv + BN (inference). One thread per (b,pix,ch).
// ---------------------------------------------------------------------------
__global__ void conv_bn(const float* __restrict__ x1, const float* __restrict__ w,
                        const float* __restrict__ g, const float* __restrict__ b,
                        const float* __restrict__ mean, const float* __restrict__ var,
                        float* __restrict__ x2) {
  long tid = (long)blockIdx.x * 256 + threadIdx.x;
  int  ch  = (int)(tid % DIM_);
  long pb  = tid / DIM_;
  int  pix = (int)(pb & 4095);
  int  bb  = (int)(pb >> 12);
  int  r = pix >> 6, c = pix & 63;
  float acc = 0.f;
  #pragma unroll
  for (int dr = -1; dr <= 1; dr++)
    #pragma unroll
    for (int dc = -1; dc <= 1; dc++) {
      int rr = r + dr, cc = c + dc;
      if (rr >= 0 && rr < 64 && cc >= 0 && cc < 64)
        acc += x1[((long)bb * 4096 + rr * 64 + cc) * DIM_ + ch] * w[ch * 9 + (dr + 1) * 3 + (dc + 1)];
    }
  float sc = g[ch] * rsqrtf(var[ch] + EPS_);
  x2[tid] = (acc - mean[ch]) * sc + b[ch];
}

// ---------------------------------------------------------------------------
// bf16 MFMA GEMM, C(MxN) = A(MxK) @ Bt(NxK)^T, 128x128 tile, 4 waves (2x2),
// BK=32, global_load_lds(16B) staging, fused epilogues.
// MODE 0: qkv   -> bf16 out = acc + bias
// MODE 1: proj  -> window-reverse scatter: X1 = x + acc + bias (valid pixels)
// MODE 2: fc1   -> bf16 out = gelu_exact(acc + bias)
// MODE 3: fc2   -> f32 out = acc + bias + res
// ---------------------------------------------------------------------------
template <int MODE>
__global__ void __launch_bounds__(256)
gemm_bf16_128(const __bf16* __restrict__ A, const __bf16* __restrict__ Bt,
              const float* __restrict__ bias, int K, int N,
              float* __restrict__ outf, __bf16* __restrict__ outb,
              const float* __restrict__ res) {
  __shared__ __align__(16) __bf16 sA[128 * 32];
  __shared__ __align__(16) __bf16 sB[128 * 32];
  int tid = threadIdx.x, lane = tid & 63, wid = tid >> 6;
  int wm = wid >> 1, wn = wid & 1;
  int quad = lane >> 4, l16 = lane & 15;
  long tileM = (long)blockIdx.x * 128;
  long tileN = (long)blockIdx.y * 128;

  f32x4 acc[4][4];
  #pragma unroll
  for (int i = 0; i < 4; i++)
    #pragma unroll
    for (int j = 0; j < 4; j++) acc[i][j] = (f32x4){0.f, 0.f, 0.f, 0.f};

  // staging: 8 chunks of 1KB per tile; wave handles chunks wid and wid+4.
  // chunk ci covers rows [ci*16, ci*16+16), lane -> row ci*16 + l/4, 16B piece l%4.
  int rA = wid * 16 + (lane >> 2);
  const __bf16* gA = A  + (tileM + rA) * (long)K + ((lane & 3) << 3);
  const __bf16* gB = Bt + (tileN + rA) * (long)K + ((lane & 3) << 3);
  __bf16* lA0 = sA + (wid << 9);
  __bf16* lA1 = sA + ((wid + 4) << 9);
  __bf16* lB0 = sB + (wid << 9);
  __bf16* lB1 = sB + ((wid + 4) << 9);
  const long rowskip = 64 * (long)K;

  for (int k0 = 0; k0 < K; k0 += 32) {
    gload_lds16(gA + k0,           lA0);
    gload_lds16(gA + k0 + rowskip, lA1);
    gload_lds16(gB + k0,           lB0);
    gload_lds16(gB + k0 + rowskip, lB1);
    __syncthreads();   // drains vmcnt -> staging visible
    bf16x8 af[4], bfr[4];
    #pragma unroll
    for (int mt = 0; mt < 4; mt++)
      af[mt] = *(const bf16x8*)(sA + ((wm * 64 + mt * 16 + l16) << 5) + (quad << 3));
    #pragma unroll
    for (int nt = 0; nt < 4; nt++)
      bfr[nt] = *(const bf16x8*)(sB + ((wn * 64 + nt * 16 + l16) << 5) + (quad << 3));
    #pragma unroll
    for (int mt = 0; mt < 4; mt++)
      #pragma unroll
      for (int nt = 0; nt < 4; nt++)
        acc[mt][nt] = __builtin_amdgcn_mfma_f32_16x16x32_bf16(af[mt], bfr[nt], acc[mt][nt], 0, 0, 0);
    __syncthreads();   // protect LDS before next stage
  }

  float bcol[4];
  #pragma unroll
  for (int nt = 0; nt < 4; nt++) bcol[nt] = bias[tileN + wn * 64 + nt * 16 + l16];

  #pragma unroll
  for (int mt = 0; mt < 4; mt++) {
    #pragma unroll
    for (int r = 0; r < 4; r++) {
      long row = tileM + wm * 64 + mt * 16 + quad * 4 + r;
      if (MODE == 0) {
        __bf16* orow = outb + row * (long)N;
        #pragma unroll
        for (int nt = 0; nt < 4; nt++)
          orow[tileN + wn * 64 + nt * 16 + l16] = (__bf16)(acc[mt][nt][r] + bcol[nt]);
      } else if (MODE == 1) {
        if (row < MREAL) {
          int r32 = (int)row;
          int win = r32 / NTOK, t = r32 % NTOK;
          int rem = win % 100;
          int pr = (rem / 10) * 7 + t / 7;
          int pc = (rem % 10) * 7 + t % 7;
          if (pr < 64 && pc < 64) {
            long po = ((long)(win / 100) * 4096 + pr * 64 + pc) * DIM_;
            #pragma unroll
            for (int nt = 0; nt < 4; nt++) {
              long col = tileN + wn * 64 + nt * 16 + l16;
              outf[po + col] = res[po + col] + acc[mt][nt][r] + bcol[nt];
            }
          }
        }
      } else if (MODE == 2) {
        __bf16* orow = outb + row * (long)N;
        #pragma unroll
        for (int nt = 0; nt < 4; nt++) {
          float v = acc[mt][nt][r] + bcol[nt];
          orow[tileN + wn * 64 + nt * 16 + l16] = (__bf16)(0.5f * v * (1.f + erff(v * 0.70710678118654752f)));
        }
      } else {
        float* orow = outf + row * (long)N;
        const float* rrow = res + row * (long)N;
        #pragma unroll
        for (int nt = 0; nt < 4; nt++) {
          long col = tileN + wn * 64 + nt * 16 + l16;
          orow[col] = acc[mt][nt][r] + bcol[nt] + rrow[col];
        }
      }
    }
  }
}

// ---------------------------------------------------------------------------
extern "C" void kernel_launch(void* const* d_in, const int* in_sizes, int n_in,
                              void* d_out, int out_size, void* d_ws, size_t ws_size,
                              hipStream_t stream) {
  const float* x       = (const float*)d_in[0];
  const float* ln1_g   = (const float*)d_in[1];
  const float* ln1_b   = (const float*)d_in[2];
  const float* qkv_w   = (const float*)d_in[3];
  const float* qkv_b   = (const float*)d_in[4];
  const float* proj_w  = (const float*)d_in[5];
  const float* proj_b  = (const float*)d_in[6];
  const float* attn_b  = (const float*)d_in[7];
  const float* conv_w  = (const float*)d_in[8];
  const float* bn_g    = (const float*)d_in[9];
  const float* bn_b    = (const float*)d_in[10];
  const float* bn_mean = (const float*)d_in[11];
  const float* bn_var  = (const float*)d_in[12];
  const float* ln2_g   = (const float*)d_in[13];
  const float* ln2_b   = (const float*)d_in[14];
  const float* fc1_w   = (const float*)d_in[15];
  const float* fc1_b   = (const float*)d_in[16];
  const float* fc2_w   = (const float*)d_in[17];
  const float* fc2_b   = (const float*)d_in[18];

  // workspace layout (with aliasing; ~129.6 MB total):
  char* p = (char*)d_ws;
  __bf16* WQKV = (__bf16*)p;  p += 884736;     // 1152x384
  __bf16* WPROJ = (__bf16*)p; p += 294912;     // 384x384
  __bf16* WFC1 = (__bf16*)p;  p += 1179648;    // 1536x384
  __bf16* WFC2 = (__bf16*)p;  p += 1179648;    // 384x1536
  char* region = p;           p += 75694080;   // xn+qkv+o   ||  xln2+h1
  float* X1 = (float*)p;      p += 25165824;
  float* X2 = (float*)p;      p += 25165824;
  __bf16* XN   = (__bf16*)region;                 // 19712x384
  __bf16* QKVB = (__bf16*)(region + 15138816);    // 19712x1152
  __bf16* OBUF = (__bf16*)(region + 60555264);    // 19712x384
  __bf16* XLN2 = (__bf16*)region;                 // 16384x384  (aliases XN, dead)
  __bf16* H1   = (__bf16*)(region + 15138816);    // 16384x1536 (aliases QKVB+OBUF, dead)
  float* OUT = (float*)d_out;

  transpose_cast<<<(442368 + 255) / 256, 256, 0, stream>>>(qkv_w, WQKV, DIM_, QKVD);
  transpose_cast<<<(147456 + 255) / 256, 256, 0, stream>>>(proj_w, WPROJ, DIM_, DIM_);
  transpose_cast<<<(589824 + 255) / 256, 256, 0, stream>>>(fc1_w, WFC1, DIM_, HIDD);
  transpose_cast<<<(589824 + 255) / 256, 256, 0, stream>>>(fc2_w, WFC2, HIDD, DIM_);

  ln1_window<<<MPAD, 128, 0, stream>>>(x, ln1_g, ln1_b, XN);

  gemm_bf16_128<0><<<dim3(MPAD / 128, QKVD / 128), 256, 0, stream>>>(
      XN, WQKV, qkv_b, DIM_, QKVD, nullptr, QKVB, nullptr);

  attn_kernel<<<NWIN * 12, 256, 0, stream>>>(QKVB, attn_b, OBUF);

  gemm_bf16_128<1><<<dim3(MPAD / 128, DIM_ / 128), 256, 0, stream>>>(
      OBUF, WPROJ, proj_b, DIM_, DIM_, X1, nullptr, x);

  conv_bn<<<(TOKENS * DIM_) / 256, 256, 0, stream>>>(X1, conv_w, bn_g, bn_b, bn_mean, bn_var, X2);

  ln2_kernel<<<TOKENS, 128, 0, stream>>>(X2, ln2_g, ln2_b, XLN2);

  gemm_bf16_128<2><<<dim3(TOKENS / 128, HIDD / 128), 256, 0, stream>>>(
      XLN2, WFC1, fc1_b, DIM_, HIDD, nullptr, H1, nullptr);

  gemm_bf16_128<3><<<dim3(TOKENS / 128, DIM_ / 128), 256, 0, stream>>>(
      H1, WFC2, fc2_b, HIDD, DIM_, OUT, nullptr, X2);
}

// Round 2
// 366.226 us; speedup vs baseline: 1.1573x; 1.1573x over previous
//
#include <hip/hip_runtime.h>
#include <cstdint>

// ---------------------------------------------------------------------------
// TinyViT block on gfx950. Round 2: MFMA attention (per-(win,head) wave),
// bias+mask precomputed table; GEMMs unchanged from round 1 (verified).
// ---------------------------------------------------------------------------

typedef __bf16 bf16x8 __attribute__((ext_vector_type(8)));
typedef float  f32x4  __attribute__((ext_vector_type(4)));

#define DIM_    384
#define QKVD    1152
#define HIDD    1536
#define NTOK    49
#define NWIN    400
#define MPAD    19712     /* 154*128 */
#define MREAL   19600
#define TOKENS  16384     /* 4*4096 */
#define SCALE_  0.17677669529663689f
#define EPS_    1e-5f

__device__ __forceinline__ void gload_lds16(const void* g, void* l) {
  __builtin_amdgcn_global_load_lds(
      (__attribute__((address_space(1))) void*)g,
      (__attribute__((address_space(3))) void*)l, 16, 0, 0);
}

// ---------------------------------------------------------------------------
// Weight transpose + cast: dst[n*K+k] = bf16(src[k*N+n])   (K x N -> N x K)
// ---------------------------------------------------------------------------
__global__ void transpose_cast(const float* __restrict__ src, __bf16* __restrict__ dst,
                               int K, int N) {
  long id = (long)blockIdx.x * 256 + threadIdx.x;
  if (id >= (long)K * N) return;
  int  k = (int)(id % K);
  long n = id / K;
  dst[n * K + k] = (__bf16)src[(long)k * N + n];
}

// ---------------------------------------------------------------------------
// Expand attn_bias[12][49] -> bm[12][64][64] fp32, with column-mask baked in:
// bm[h][q][kk] = bias for q,kk<49 ; -1e30 for kk>=49 ; 0 for q>=49.
// idx = |q/7-kk/7|*7 + |q%7-kk%7| (derived from BIAS_IDXS construction order).
// ---------------------------------------------------------------------------
__global__ void bias_expand(const float* __restrict__ ab, float* __restrict__ bm) {
  int id = blockIdx.x * 256 + threadIdx.x;           // 12*64*64 = 49152
  int h = id >> 12, q = (id >> 6) & 63, kk = id & 63;
  float v;
  if (kk >= NTOK)      v = -1e30f;
  else if (q >= NTOK)  v = 0.f;
  else {
    int idx = abs(q / 7 - kk / 7) * 7 + abs(q % 7 - kk % 7);
    v = ab[h * NTOK + idx];
  }
  bm[id] = v;
}

// ---------------------------------------------------------------------------
// LN1 + window partition. Block = one padded-window token (19712), 128 thr.
// ---------------------------------------------------------------------------
__global__ void ln1_window(const float* __restrict__ x, const float* __restrict__ gam,
                           const float* __restrict__ bet, __bf16* __restrict__ xn) {
  int t   = blockIdx.x;
  int tid = threadIdx.x;
  __bf16* orow = xn + (long)t * DIM_;
  if (t >= MREAL) {
    for (int i = tid; i < DIM_; i += 128) orow[i] = (__bf16)0.f;
    return;
  }
  int win = t / NTOK, tt = t % NTOK;
  int bb = win / 100, rem = win % 100;
  int r = (rem / 10) * 7 + tt / 7;
  int c = (rem % 10) * 7 + tt % 7;
  if (r >= 64 || c >= 64) {
    for (int i = tid; i < DIM_; i += 128) orow[i] = (__bf16)bet[i];
    return;
  }
  const float* xr = x + ((long)bb * 4096 + r * 64 + c) * DIM_;
  float v0 = xr[tid], v1 = xr[tid + 128], v2 = xr[tid + 256];
  float s = v0 + v1 + v2, s2 = v0 * v0 + v1 * v1 + v2 * v2;
  for (int off = 32; off; off >>= 1) { s += __shfl_down(s, off); s2 += __shfl_down(s2, off); }
  __shared__ float red[4];
  if ((tid & 63) == 0) { red[tid >> 6] = s; red[2 + (tid >> 6)] = s2; }
  __syncthreads();
  float S = red[0] + red[1], S2 = red[2] + red[3];
  float m  = S * (1.f / DIM_);
  float rs = rsqrtf(S2 * (1.f / DIM_) - m * m + EPS_);
  orow[tid]       = (__bf16)((v0 - m) * rs * gam[tid]       + bet[tid]);
  orow[tid + 128] = (__bf16)((v1 - m) * rs * gam[tid + 128] + bet[tid + 128]);
  orow[tid + 256] = (__bf16)((v2 - m) * rs * gam[tid + 256] + bet[tid + 256]);
}

// ---------------------------------------------------------------------------
// LN2 (plain, over X2). Block = one token (16384), 128 threads.
// ---------------------------------------------------------------------------
__global__ void ln2_kernel(const float* __restrict__ x2, const float* __restrict__ gam,
                           const float* __restrict__ bet, __bf16* __restrict__ out) {
  long t  = blockIdx.x;
  int tid = threadIdx.x;
  const float* xr = x2 + t * DIM_;
  float v0 = xr[tid], v1 = xr[tid + 128], v2 = xr[tid + 256];
  float s = v0 + v1 + v2, s2 = v0 * v0 + v1 * v1 + v2 * v2;
  for (int off = 32; off; off >>= 1) { s += __shfl_down(s, off); s2 += __shfl_down(s2, off); }
  __shared__ float red[4];
  if ((tid & 63) == 0) { red[tid >> 6] = s; red[2 + (tid >> 6)] = s2; }
  __syncthreads();
  float S = red[0] + red[1], S2 = red[2] + red[3];
  float m  = S * (1.f / DIM_);
  float rs = rsqrtf(S2 * (1.f / DIM_) - m * m + EPS_);
  __bf16* orow = out + t * DIM_;
  orow[tid]       = (__bf16)((v0 - m) * rs * gam[tid]       + bet[tid]);
  orow[tid + 128] = (__bf16)((v1 - m) * rs * gam[tid + 128] + bet[tid + 128]);
  orow[tid + 256] = (__bf16)((v2 - m) * rs * gam[tid + 256] + bet[tid + 256]);
}

// ---------------------------------------------------------------------------
// MFMA attention: one 64-thread block per (window, head). 4800 blocks.
// QK^T and PV via mfma_f32_16x16x32_bf16 (49 padded to 64).
// - Q/K fragments loaded directly from global in A/B layout (rows >=49 read
//   neighbor-window data: harmless -- C[m] depends only on A-row m, and key
//   columns >=49 are masked to -1e30 via the precomputed bias table).
// - V transposed into LDS (2-way-conflict-free scatter); P -> LDS (C-layout
//   to A-layout round trip).
// ---------------------------------------------------------------------------
__global__ __launch_bounds__(64) void attn_mfma(const __bf16* __restrict__ qkv,
                                                const float* __restrict__ bm,
                                                __bf16* __restrict__ o) {
  int blk = blockIdx.x;
  int win = blk / 12, h = blk % 12;
  int lane = threadIdx.x;
  int quad = lane >> 4, l16 = lane & 15;

  __shared__ __align__(16) __bf16 Vt[32][72];   // Vt[d][kk]
  __shared__ __align__(16) __bf16 P[64][72];    // P[q][kk]

  const __bf16* base = qkv + (long)win * NTOK * QKVD + h * 96;
  // rows win*49 .. win*49+63: max 399*49+63 = 19614 < 19712 -> in-bounds.

  // Q (A-operand) and K (B-operand) fragments: row = t*16+l16, k = quad*8..+7
  bf16x8 qf[4], kf[4];
  #pragma unroll
  for (int t = 0; t < 4; t++) {
    const __bf16* rp = base + (long)(t * 16 + l16) * QKVD + quad * 8;
    qf[t] = *(const bf16x8*)(rp);
    kf[t] = *(const bf16x8*)(rp + 32);
  }
  // Stage V transposed: lane = kk row, 32 d values -> Vt[d][kk]
  {
    const __bf16* vp = base + (long)lane * QKVD + 64;
    bf16x8 vv[4];
    #pragma unroll
    for (int i = 0; i < 4; i++) vv[i] = *(const bf16x8*)(vp + i * 8);
    #pragma unroll
    for (int i = 0; i < 4; i++)
      #pragma unroll
      for (int j = 0; j < 8; j++) Vt[i * 8 + j][lane] = vv[i][j];
  }

  // ---- scores S[q][kk], q = mt*16+quad*4+r, kk = nt*16+l16 ----
  f32x4 S[4][4];
  #pragma unroll
  for (int i = 0; i < 4; i++)
    #pragma unroll
    for (int j = 0; j < 4; j++) S[i][j] = (f32x4){0.f, 0.f, 0.f, 0.f};
  #pragma unroll
  for (int mt = 0; mt < 4; mt++)
    #pragma unroll
    for (int nt = 0; nt < 4; nt++)
      S[mt][nt] = __builtin_amdgcn_mfma_f32_16x16x32_bf16(qf[mt], kf[nt], S[mt][nt], 0, 0, 0);

  // bias + scale (mask baked into bm for kk>=49)
  const float* bmh = bm + h * 4096;
  #pragma unroll
  for (int mt = 0; mt < 4; mt++)
    #pragma unroll
    for (int r = 0; r < 4; r++) {
      int q = mt * 16 + quad * 4 + r;
      #pragma unroll
      for (int nt = 0; nt < 4; nt++)
        S[mt][nt][r] = S[mt][nt][r] * SCALE_ + bmh[q * 64 + nt * 16 + l16];
    }

  // softmax per row q: reduce over nt (register) x l16 (shfl within 16-group)
  #pragma unroll
  for (int mt = 0; mt < 4; mt++)
    #pragma unroll
    for (int r = 0; r < 4; r++) {
      float mx = fmaxf(fmaxf(S[mt][0][r], S[mt][1][r]), fmaxf(S[mt][2][r], S[mt][3][r]));
      #pragma unroll
      for (int off = 1; off < 16; off <<= 1) mx = fmaxf(mx, __shfl_xor(mx, off));
      float sum = 0.f;
      #pragma unroll
      for (int nt = 0; nt < 4; nt++) {
        float e = __expf(S[mt][nt][r] - mx);
        S[mt][nt][r] = e;
        sum += e;
      }
      #pragma unroll
      for (int off = 1; off < 16; off <<= 1) sum += __shfl_xor(sum, off);
      float inv = 1.f / sum;
      #pragma unroll
      for (int nt = 0; nt < 4; nt++) S[mt][nt][r] *= inv;
    }

  // P -> LDS in A-layout
  #pragma unroll
  for (int mt = 0; mt < 4; mt++)
    #pragma unroll
    for (int r = 0; r < 4; r++) {
      int q = mt * 16 + quad * 4 + r;
      #pragma unroll
      for (int nt = 0; nt < 4; nt++)
        P[q][nt * 16 + l16] = (__bf16)S[mt][nt][r];
    }
  __syncthreads();   // single-wave: waitcnt + barrier, covers Vt + P writes

  // ---- O[q][d] = sum_kk P[q][kk] * Vt[d][kk] ----
  f32x4 O[4][2];
  #pragma unroll
  for (int i = 0; i < 4; i++)
    #pragma unroll
    for (int j = 0; j < 2; j++) O[i][j] = (f32x4){0.f, 0.f, 0.f, 0.f};
  #pragma unroll
  for (int kt = 0; kt < 2; kt++) {
    bf16x8 pf[4], vf[2];
    #pragma unroll
    for (int mt = 0; mt < 4; mt++)
      pf[mt] = *(const bf16x8*)(&P[mt * 16 + l16][kt * 32 + quad * 8]);
    #pragma unroll
    for (int nt = 0; nt < 2; nt++)
      vf[nt] = *(const bf16x8*)(&Vt[nt * 16 + l16][kt * 32 + quad * 8]);
    #pragma unroll
    for (int mt = 0; mt < 4; mt++)
      #pragma unroll
      for (int nt = 0; nt < 2; nt++)
        O[mt][nt] = __builtin_amdgcn_mfma_f32_16x16x32_bf16(pf[mt], vf[nt], O[mt][nt], 0, 0, 0);
  }

  // store: O rows q<49 only
  __bf16* ob = o + (long)win * NTOK * DIM_ + h * 32;
  #pragma unroll
  for (int mt = 0; mt < 4; mt++)
    #pragma unroll
    for (int r = 0; r < 4; r++) {
      int q = mt * 16 + quad * 4 + r;
      if (q < NTOK) {
        #pragma unroll
        for (int nt = 0; nt < 2; nt++)
          ob[(long)q * DIM_ + nt * 16 + l16] = (__bf16)O[mt][nt][r];
      }
    }
}

// ---------------------------------------------------------------------------
// Depthwise 3x3 conv + BN (inference). One thread per (b,pix,ch).
// ---------------------------------------------------------------------------
__global__ void conv_bn(const float* __restrict__ x1, const float* __restrict__ w,
                        const float* __restrict__ g, const float* __restrict__ b,
                        const float* __restrict__ mean, const float* __restrict__ var,
                        float* __restrict__ x2) {
  long tid = (long)blockIdx.x * 256 + threadIdx.x;
  int  ch  = (int)(tid % DIM_);
  long pb  = tid / DIM_;
  int  pix = (int)(pb & 4095);
  int  bb  = (int)(pb >> 12);
  int  r = pix >> 6, c = pix & 63;
  float acc = 0.f;
  #pragma unroll
  for (int dr = -1; dr <= 1; dr++)
    #pragma unroll
    for (int dc = -1; dc <= 1; dc++) {
      int rr = r + dr, cc = c + dc;
      if (rr >= 0 && rr < 64 && cc >= 0 && cc < 64)
        acc += x1[((long)bb * 4096 + rr * 64 + cc) * DIM_ + ch] * w[ch * 9 + (dr + 1) * 3 + (dc + 1)];
    }
  float sc = g[ch] * rsqrtf(var[ch] + EPS_);
  x2[tid] = (acc - mean[ch]) * sc + b[ch];
}

// ---------------------------------------------------------------------------
// bf16 MFMA GEMM, C(MxN) = A(MxK) @ Bt(NxK)^T, 128x128 tile, 4 waves (2x2),
// BK=32, global_load_lds(16B) staging, fused epilogues.
// MODE 0: qkv   -> bf16 out = acc + bias
// MODE 1: proj  -> window-reverse scatter: X1 = x + acc + bias (valid pixels)
// MODE 2: fc1   -> bf16 out = gelu_exact(acc + bias)
// MODE 3: fc2   -> f32 out = acc + bias + res
// ---------------------------------------------------------------------------
template <int MODE>
__global__ void __launch_bounds__(256)
gemm_bf16_128(const __bf16* __restrict__ A, const __bf16* __restrict__ Bt,
              const float* __restrict__ bias, int K, int N,
              float* __restrict__ outf, __bf16* __restrict__ outb,
              const float* __restrict__ res) {
  __shared__ __align__(16) __bf16 sA[128 * 32];
  __shared__ __align__(16) __bf16 sB[128 * 32];
  int tid = threadIdx.x, lane = tid & 63, wid = tid >> 6;
  int wm = wid >> 1, wn = wid & 1;
  int quad = lane >> 4, l16 = lane & 15;
  long tileM = (long)blockIdx.x * 128;
  long tileN = (long)blockIdx.y * 128;

  f32x4 acc[4][4];
  #pragma unroll
  for (int i = 0; i < 4; i++)
    #pragma unroll
    for (int j = 0; j < 4; j++) acc[i][j] = (f32x4){0.f, 0.f, 0.f, 0.f};

  int rA = wid * 16 + (lane >> 2);
  const __bf16* gA = A  + (tileM + rA) * (long)K + ((lane & 3) << 3);
  const __bf16* gB = Bt + (tileN + rA) * (long)K + ((lane & 3) << 3);
  __bf16* lA0 = sA + (wid << 9);
  __bf16* lA1 = sA + ((wid + 4) << 9);
  __bf16* lB0 = sB + (wid << 9);
  __bf16* lB1 = sB + ((wid + 4) << 9);
  const long rowskip = 64 * (long)K;

  for (int k0 = 0; k0 < K; k0 += 32) {
    gload_lds16(gA + k0,           lA0);
    gload_lds16(gA + k0 + rowskip, lA1);
    gload_lds16(gB + k0,           lB0);
    gload_lds16(gB + k0 + rowskip, lB1);
    __syncthreads();
    bf16x8 af[4], bfr[4];
    #pragma unroll
    for (int mt = 0; mt < 4; mt++)
      af[mt] = *(const bf16x8*)(sA + ((wm * 64 + mt * 16 + l16) << 5) + (quad << 3));
    #pragma unroll
    for (int nt = 0; nt < 4; nt++)
      bfr[nt] = *(const bf16x8*)(sB + ((wn * 64 + nt * 16 + l16) << 5) + (quad << 3));
    #pragma unroll
    for (int mt = 0; mt < 4; mt++)
      #pragma unroll
      for (int nt = 0; nt < 4; nt++)
        acc[mt][nt] = __builtin_amdgcn_mfma_f32_16x16x32_bf16(af[mt], bfr[nt], acc[mt][nt], 0, 0, 0);
    __syncthreads();
  }

  float bcol[4];
  #pragma unroll
  for (int nt = 0; nt < 4; nt++) bcol[nt] = bias[tileN + wn * 64 + nt * 16 + l16];

  #pragma unroll
  for (int mt = 0; mt < 4; mt++) {
    #pragma unroll
    for (int r = 0; r < 4; r++) {
      long row = tileM + wm * 64 + mt * 16 + quad * 4 + r;
      if (MODE == 0) {
        __bf16* orow = outb + row * (long)N;
        #pragma unroll
        for (int nt = 0; nt < 4; nt++)
          orow[tileN + wn * 64 + nt * 16 + l16] = (__bf16)(acc[mt][nt][r] + bcol[nt]);
      } else if (MODE == 1) {
        if (row < MREAL) {
          int r32 = (int)row;
          int win = r32 / NTOK, t = r32 % NTOK;
          int rem = win % 100;
          int pr = (rem / 10) * 7 + t / 7;
          int pc = (rem % 10) * 7 + t % 7;
          if (pr < 64 && pc < 64) {
            long po = ((long)(win / 100) * 4096 + pr * 64 + pc) * DIM_;
            #pragma unroll
            for (int nt = 0; nt < 4; nt++) {
              long col = tileN + wn * 64 + nt * 16 + l16;
              outf[po + col] = res[po + col] + acc[mt][nt][r] + bcol[nt];
            }
          }
        }
      } else if (MODE == 2) {
        __bf16* orow = outb + row * (long)N;
        #pragma unroll
        for (int nt = 0; nt < 4; nt++) {
          float v = acc[mt][nt][r] + bcol[nt];
          orow[tileN + wn * 64 + nt * 16 + l16] = (__bf16)(0.5f * v * (1.f + erff(v * 0.70710678118654752f)));
        }
      } else {
        float* orow = outf + row * (long)N;
        const float* rrow = res + row * (long)N;
        #pragma unroll
        for (int nt = 0; nt < 4; nt++) {
          long col = tileN + wn * 64 + nt * 16 + l16;
          orow[col] = acc[mt][nt][r] + bcol[nt] + rrow[col];
        }
      }
    }
  }
}

// ---------------------------------------------------------------------------
extern "C" void kernel_launch(void* const* d_in, const int* in_sizes, int n_in,
                              void* d_out, int out_size, void* d_ws, size_t ws_size,
                              hipStream_t stream) {
  const float* x       = (const float*)d_in[0];
  const float* ln1_g   = (const float*)d_in[1];
  const float* ln1_b   = (const float*)d_in[2];
  const float* qkv_w   = (const float*)d_in[3];
  const float* qkv_b   = (const float*)d_in[4];
  const float* proj_w  = (const float*)d_in[5];
  const float* proj_b  = (const float*)d_in[6];
  const float* attn_b  = (const float*)d_in[7];
  const float* conv_w  = (const float*)d_in[8];
  const float* bn_g    = (const float*)d_in[9];
  const float* bn_b    = (const float*)d_in[10];
  const float* bn_mean = (const float*)d_in[11];
  const float* bn_var  = (const float*)d_in[12];
  const float* ln2_g   = (const float*)d_in[13];
  const float* ln2_b   = (const float*)d_in[14];
  const float* fc1_w   = (const float*)d_in[15];
  const float* fc1_b   = (const float*)d_in[16];
  const float* fc2_w   = (const float*)d_in[17];
  const float* fc2_b   = (const float*)d_in[18];

  // workspace layout (aliasing; ~129.6 MB total):
  char* p = (char*)d_ws;
  __bf16* WQKV = (__bf16*)p;  p += 884736;     // 1152x384
  __bf16* WPROJ = (__bf16*)p; p += 294912;     // 384x384
  __bf16* WFC1 = (__bf16*)p;  p += 1179648;    // 1536x384
  __bf16* WFC2 = (__bf16*)p;  p += 1179648;    // 384x1536
  char* region = p;           p += 75694080;
  float* X1 = (float*)p;      p += 25165824;
  float* X2 = (float*)p;      p += 25165824;
  __bf16* XN   = (__bf16*)region;                 // 19712x384 (dead after QKV gemm)
  float*  BM   = (float*)region;                  // 12x64x64 bias table (aliases XN)
  __bf16* QKVB = (__bf16*)(region + 15138816);    // 19712x1152
  __bf16* OBUF = (__bf16*)(region + 60555264);    // 19712x384
  __bf16* XLN2 = (__bf16*)region;                 // 16384x384  (aliases XN/BM, dead)
  __bf16* H1   = (__bf16*)(region + 15138816);    // 16384x1536 (aliases QKVB+OBUF, dead)
  float* OUT = (float*)d_out;

  transpose_cast<<<(442368 + 255) / 256, 256, 0, stream>>>(qkv_w, WQKV, DIM_, QKVD);
  transpose_cast<<<(147456 + 255) / 256, 256, 0, stream>>>(proj_w, WPROJ, DIM_, DIM_);
  transpose_cast<<<(589824 + 255) / 256, 256, 0, stream>>>(fc1_w, WFC1, DIM_, HIDD);
  transpose_cast<<<(589824 + 255) / 256, 256, 0, stream>>>(fc2_w, WFC2, HIDD, DIM_);

  ln1_window<<<MPAD, 128, 0, stream>>>(x, ln1_g, ln1_b, XN);

  gemm_bf16_128<0><<<dim3(MPAD / 128, QKVD / 128), 256, 0, stream>>>(
      XN, WQKV, qkv_b, DIM_, QKVD, nullptr, QKVB, nullptr);

  // XN dead now; BM aliases it. Build bias table, then attention.
  bias_expand<<<192, 256, 0, stream>>>(attn_b, BM);

  attn_mfma<<<NWIN * 12, 64, 0, stream>>>(QKVB, BM, OBUF);

  gemm_bf16_128<1><<<dim3(MPAD / 128, DIM_ / 128), 256, 0, stream>>>(
      OBUF, WPROJ, proj_b, DIM_, DIM_, X1, nullptr, x);

  conv_bn<<<(TOKENS * DIM_) / 256, 256, 0, stream>>>(X1, conv_w, bn_g, bn_b, bn_mean, bn_var, X2);

  ln2_kernel<<<TOKENS, 128, 0, stream>>>(X2, ln2_g, ln2_b, XLN2);

  gemm_bf16_128<2><<<dim3(TOKENS / 128, HIDD / 128), 256, 0, stream>>>(
      XLN2, WFC1, fc1_b, DIM_, HIDD, nullptr, H1, nullptr);

  gemm_bf16_128<3><<<dim3(TOKENS / 128, DIM_ / 128), 256, 0, stream>>>(
      H1, WFC2, fc2_b, HIDD, DIM_, OUT, nullptr, X2);
}

// Round 3
// 330.316 us; speedup vs baseline: 1.2831x; 1.1087x over previous
//
#include <hip/hip_runtime.h>
#include <cstdint>

// ---------------------------------------------------------------------------
// TinyViT block on gfx950. Round 3: fused conv+BN+LN2 (float4, 4 ch/lane),
// MFMA attention + m97-pattern GEMMs unchanged (verified rounds 1-2).
// ---------------------------------------------------------------------------

typedef __bf16 bf16x8 __attribute__((ext_vector_type(8)));
typedef __bf16 bf16x4 __attribute__((ext_vector_type(4)));
typedef float  f32x4  __attribute__((ext_vector_type(4)));

#define DIM_    384
#define QKVD    1152
#define HIDD    1536
#define NTOK    49
#define NWIN    400
#define MPAD    19712     /* 154*128 */
#define MREAL   19600
#define TOKENS  16384     /* 4*4096 */
#define SCALE_  0.17677669529663689f
#define EPS_    1e-5f

__device__ __forceinline__ void gload_lds16(const void* g, void* l) {
  __builtin_amdgcn_global_load_lds(
      (__attribute__((address_space(1))) void*)g,
      (__attribute__((address_space(3))) void*)l, 16, 0, 0);
}

// ---------------------------------------------------------------------------
// Weight transpose + cast: dst[n*K+k] = bf16(src[k*N+n])   (K x N -> N x K)
// ---------------------------------------------------------------------------
__global__ void transpose_cast(const float* __restrict__ src, __bf16* __restrict__ dst,
                               int K, int N) {
  long id = (long)blockIdx.x * 256 + threadIdx.x;
  if (id >= (long)K * N) return;
  int  k = (int)(id % K);
  long n = id / K;
  dst[n * K + k] = (__bf16)src[(long)k * N + n];
}

// conv_w [384][9] -> wT [9][384] (float, for float4 tap loads)
__global__ void convw_transpose(const float* __restrict__ w, float* __restrict__ wT) {
  int id = blockIdx.x * 256 + threadIdx.x;
  if (id >= 3456) return;
  int ch = id / 9, k = id % 9;
  wT[k * 384 + ch] = w[id];
}

// ---------------------------------------------------------------------------
// Expand attn_bias[12][49] -> bm[12][64][64] fp32, column-mask baked in.
// ---------------------------------------------------------------------------
__global__ void bias_expand(const float* __restrict__ ab, float* __restrict__ bm) {
  int id = blockIdx.x * 256 + threadIdx.x;           // 12*64*64 = 49152
  int h = id >> 12, q = (id >> 6) & 63, kk = id & 63;
  float v;
  if (kk >= NTOK)      v = -1e30f;
  else if (q >= NTOK)  v = 0.f;
  else {
    int idx = abs(q / 7 - kk / 7) * 7 + abs(q % 7 - kk % 7);
    v = ab[h * NTOK + idx];
  }
  bm[id] = v;
}

// ---------------------------------------------------------------------------
// LN1 + window partition. Block = one padded-window token (19712), 128 thr.
// ---------------------------------------------------------------------------
__global__ void ln1_window(const float* __restrict__ x, const float* __restrict__ gam,
                           const float* __restrict__ bet, __bf16* __restrict__ xn) {
  int t   = blockIdx.x;
  int tid = threadIdx.x;
  __bf16* orow = xn + (long)t * DIM_;
  if (t >= MREAL) {
    for (int i = tid; i < DIM_; i += 128) orow[i] = (__bf16)0.f;
    return;
  }
  int win = t / NTOK, tt = t % NTOK;
  int bb = win / 100, rem = win % 100;
  int r = (rem / 10) * 7 + tt / 7;
  int c = (rem % 10) * 7 + tt % 7;
  if (r >= 64 || c >= 64) {
    for (int i = tid; i < DIM_; i += 128) orow[i] = (__bf16)bet[i];
    return;
  }
  const float* xr = x + ((long)bb * 4096 + r * 64 + c) * DIM_;
  float v0 = xr[tid], v1 = xr[tid + 128], v2 = xr[tid + 256];
  float s = v0 + v1 + v2, s2 = v0 * v0 + v1 * v1 + v2 * v2;
  for (int off = 32; off; off >>= 1) { s += __shfl_down(s, off); s2 += __shfl_down(s2, off); }
  __shared__ float red[4];
  if ((tid & 63) == 0) { red[tid >> 6] = s; red[2 + (tid >> 6)] = s2; }
  __syncthreads();
  float S = red[0] + red[1], S2 = red[2] + red[3];
  float m  = S * (1.f / DIM_);
  float rs = rsqrtf(S2 * (1.f / DIM_) - m * m + EPS_);
  orow[tid]       = (__bf16)((v0 - m) * rs * gam[tid]       + bet[tid]);
  orow[tid + 128] = (__bf16)((v1 - m) * rs * gam[tid + 128] + bet[tid + 128]);
  orow[tid + 256] = (__bf16)((v2 - m) * rs * gam[tid + 256] + bet[tid + 256]);
}

// ---------------------------------------------------------------------------
// Fused depthwise 3x3 conv + BN + LN2. Block = 4 pixels x 96 lanes (384 thr).
// Each lane: 4 channels (float4). Writes X2 (fp32, fc2 residual) and
// XLN2 (bf16, fc1 input). Replaces conv_bn + ln2_kernel.
// ---------------------------------------------------------------------------
__global__ __launch_bounds__(384) void conv_bn_ln2(
    const float* __restrict__ x1, const float* __restrict__ wT,
    const float* __restrict__ bng, const float* __restrict__ bnb,
    const float* __restrict__ mean, const float* __restrict__ var,
    const float* __restrict__ g2, const float* __restrict__ b2,
    float* __restrict__ x2, __bf16* __restrict__ xln2) {
  int tid = threadIdx.x;
  int p = tid / 96, g = tid % 96;
  int pix = blockIdx.x * 4 + p;            // 0..16383
  int bb = pix >> 12, rc = pix & 4095;
  int r = rc >> 6, c = rc & 63;
  int ch = g << 2;

  f32x4 acc = (f32x4){0.f, 0.f, 0.f, 0.f};
  #pragma unroll
  for (int dr = -1; dr <= 1; dr++) {
    int rr = r + dr;
    if (rr < 0 || rr >= 64) continue;
    #pragma unroll
    for (int dc = -1; dc <= 1; dc++) {
      int cc = c + dc;
      if (cc < 0 || cc >= 64) continue;
      f32x4 xv = *(const f32x4*)(x1 + ((long)bb * 4096 + rr * 64 + cc) * DIM_ + ch);
      f32x4 wv = *(const f32x4*)(wT + ((dr + 1) * 3 + (dc + 1)) * DIM_ + ch);
      acc += xv * wv;
    }
  }

  f32x4 gv = *(const f32x4*)(bng + ch);
  f32x4 vv = *(const f32x4*)(var + ch);
  f32x4 mv = *(const f32x4*)(mean + ch);
  f32x4 bv = *(const f32x4*)(bnb + ch);
  f32x4 y;
  #pragma unroll
  for (int j = 0; j < 4; j++) {
    float sc = gv[j] * rsqrtf(vv[j] + EPS_);
    y[j] = acc[j] * sc + (bv[j] - mv[j] * sc);
  }
  *(f32x4*)(x2 + (long)pix * DIM_ + ch) = y;

  // LN2 over the 384 channels of this pixel (96 lanes x 4 values each)
  __shared__ float pS[4][96], pS2[4][96], mS[4], rS[4];
  pS[p][g]  = y[0] + y[1] + y[2] + y[3];
  pS2[p][g] = y[0] * y[0] + y[1] * y[1] + y[2] * y[2] + y[3] * y[3];
  __syncthreads();
  if (g < 32) {
    float a  = pS[p][g]  + pS[p][g + 32]  + pS[p][g + 64];
    float a2 = pS2[p][g] + pS2[p][g + 32] + pS2[p][g + 64];
    #pragma unroll
    for (int off = 1; off < 32; off <<= 1) {
      a  += __shfl_xor(a, off);
      a2 += __shfl_xor(a2, off);
    }
    if (g == 0) {
      float m = a * (1.f / DIM_);
      mS[p] = m;
      rS[p] = rsqrtf(a2 * (1.f / DIM_) - m * m + EPS_);
    }
  }
  __syncthreads();
  float m = mS[p], rs = rS[p];
  f32x4 gg = *(const f32x4*)(g2 + ch);
  f32x4 b2v = *(const f32x4*)(b2 + ch);
  bf16x4 ov;
  #pragma unroll
  for (int j = 0; j < 4; j++) ov[j] = (__bf16)((y[j] - m) * rs * gg[j] + b2v[j]);
  *(bf16x4*)(xln2 + (long)pix * DIM_ + ch) = ov;
}

// ---------------------------------------------------------------------------
// MFMA attention: one 64-thread block per (window, head). 4800 blocks.
// ---------------------------------------------------------------------------
__global__ __launch_bounds__(64) void attn_mfma(const __bf16* __restrict__ qkv,
                                                const float* __restrict__ bm,
                                                __bf16* __restrict__ o) {
  int blk = blockIdx.x;
  int win = blk / 12, h = blk % 12;
  int lane = threadIdx.x;
  int quad = lane >> 4, l16 = lane & 15;

  __shared__ __align__(16) __bf16 Vt[32][72];   // Vt[d][kk]
  __shared__ __align__(16) __bf16 P[64][72];    // P[q][kk]

  const __bf16* base = qkv + (long)win * NTOK * QKVD + h * 96;

  bf16x8 qf[4], kf[4];
  #pragma unroll
  for (int t = 0; t < 4; t++) {
    const __bf16* rp = base + (long)(t * 16 + l16) * QKVD + quad * 8;
    qf[t] = *(const bf16x8*)(rp);
    kf[t] = *(const bf16x8*)(rp + 32);
  }
  {
    const __bf16* vp = base + (long)lane * QKVD + 64;
    bf16x8 vv[4];
    #pragma unroll
    for (int i = 0; i < 4; i++) vv[i] = *(const bf16x8*)(vp + i * 8);
    #pragma unroll
    for (int i = 0; i < 4; i++)
      #pragma unroll
      for (int j = 0; j < 8; j++) Vt[i * 8 + j][lane] = vv[i][j];
  }

  f32x4 S[4][4];
  #pragma unroll
  for (int i = 0; i < 4; i++)
    #pragma unroll
    for (int j = 0; j < 4; j++) S[i][j] = (f32x4){0.f, 0.f, 0.f, 0.f};
  #pragma unroll
  for (int mt = 0; mt < 4; mt++)
    #pragma unroll
    for (int nt = 0; nt < 4; nt++)
      S[mt][nt] = __builtin_amdgcn_mfma_f32_16x16x32_bf16(qf[mt], kf[nt], S[mt][nt], 0, 0, 0);

  const float* bmh = bm + h * 4096;
  #pragma unroll
  for (int mt = 0; mt < 4; mt++)
    #pragma unroll
    for (int r = 0; r < 4; r++) {
      int q = mt * 16 + quad * 4 + r;
      #pragma unroll
      for (int nt = 0; nt < 4; nt++)
        S[mt][nt][r] = S[mt][nt][r] * SCALE_ + bmh[q * 64 + nt * 16 + l16];
    }

  #pragma unroll
  for (int mt = 0; mt < 4; mt++)
    #pragma unroll
    for (int r = 0; r < 4; r++) {
      float mx = fmaxf(fmaxf(S[mt][0][r], S[mt][1][r]), fmaxf(S[mt][2][r], S[mt][3][r]));
      #pragma unroll
      for (int off = 1; off < 16; off <<= 1) mx = fmaxf(mx, __shfl_xor(mx, off));
      float sum = 0.f;
      #pragma unroll
      for (int nt = 0; nt < 4; nt++) {
        float e = __expf(S[mt][nt][r] - mx);
        S[mt][nt][r] = e;
        sum += e;
      }
      #pragma unroll
      for (int off = 1; off < 16; off <<= 1) sum += __shfl_xor(sum, off);
      float inv = 1.f / sum;
      #pragma unroll
      for (int nt = 0; nt < 4; nt++) S[mt][nt][r] *= inv;
    }

  #pragma unroll
  for (int mt = 0; mt < 4; mt++)
    #pragma unroll
    for (int r = 0; r < 4; r++) {
      int q = mt * 16 + quad * 4 + r;
      #pragma unroll
      for (int nt = 0; nt < 4; nt++)
        P[q][nt * 16 + l16] = (__bf16)S[mt][nt][r];
    }
  __syncthreads();

  f32x4 O[4][2];
  #pragma unroll
  for (int i = 0; i < 4; i++)
    #pragma unroll
    for (int j = 0; j < 2; j++) O[i][j] = (f32x4){0.f, 0.f, 0.f, 0.f};
  #pragma unroll
  for (int kt = 0; kt < 2; kt++) {
    bf16x8 pf[4], vf[2];
    #pragma unroll
    for (int mt = 0; mt < 4; mt++)
      pf[mt] = *(const bf16x8*)(&P[mt * 16 + l16][kt * 32 + quad * 8]);
    #pragma unroll
    for (int nt = 0; nt < 2; nt++)
      vf[nt] = *(const bf16x8*)(&Vt[nt * 16 + l16][kt * 32 + quad * 8]);
    #pragma unroll
    for (int mt = 0; mt < 4; mt++)
      #pragma unroll
      for (int nt = 0; nt < 2; nt++)
        O[mt][nt] = __builtin_amdgcn_mfma_f32_16x16x32_bf16(pf[mt], vf[nt], O[mt][nt], 0, 0, 0);
  }

  __bf16* ob = o + (long)win * NTOK * DIM_ + h * 32;
  #pragma unroll
  for (int mt = 0; mt < 4; mt++)
    #pragma unroll
    for (int r = 0; r < 4; r++) {
      int q = mt * 16 + quad * 4 + r;
      if (q < NTOK) {
        #pragma unroll
        for (int nt = 0; nt < 2; nt++)
          ob[(long)q * DIM_ + nt * 16 + l16] = (__bf16)O[mt][nt][r];
      }
    }
}

// ---------------------------------------------------------------------------
// bf16 MFMA GEMM, C(MxN) = A(MxK) @ Bt(NxK)^T, 128x128 tile, 4 waves (2x2),
// BK=32, global_load_lds(16B) staging, fused epilogues.
// ---------------------------------------------------------------------------
template <int MODE>
__global__ void __launch_bounds__(256)
gemm_bf16_128(const __bf16* __restrict__ A, const __bf16* __restrict__ Bt,
              const float* __restrict__ bias, int K, int N,
              float* __restrict__ outf, __bf16* __restrict__ outb,
              const float* __restrict__ res) {
  __shared__ __align__(16) __bf16 sA[128 * 32];
  __shared__ __align__(16) __bf16 sB[128 * 32];
  int tid = threadIdx.x, lane = tid & 63, wid = tid >> 6;
  int wm = wid >> 1, wn = wid & 1;
  int quad = lane >> 4, l16 = lane & 15;
  long tileM = (long)blockIdx.x * 128;
  long tileN = (long)blockIdx.y * 128;

  f32x4 acc[4][4];
  #pragma unroll
  for (int i = 0; i < 4; i++)
    #pragma unroll
    for (int j = 0; j < 4; j++) acc[i][j] = (f32x4){0.f, 0.f, 0.f, 0.f};

  int rA = wid * 16 + (lane >> 2);
  const __bf16* gA = A  + (tileM + rA) * (long)K + ((lane & 3) << 3);
  const __bf16* gB = Bt + (tileN + rA) * (long)K + ((lane & 3) << 3);
  __bf16* lA0 = sA + (wid << 9);
  __bf16* lA1 = sA + ((wid + 4) << 9);
  __bf16* lB0 = sB + (wid << 9);
  __bf16* lB1 = sB + ((wid + 4) << 9);
  const long rowskip = 64 * (long)K;

  for (int k0 = 0; k0 < K; k0 += 32) {
    gload_lds16(gA + k0,           lA0);
    gload_lds16(gA + k0 + rowskip, lA1);
    gload_lds16(gB + k0,           lB0);
    gload_lds16(gB + k0 + rowskip, lB1);
    __syncthreads();
    bf16x8 af[4], bfr[4];
    #pragma unroll
    for (int mt = 0; mt < 4; mt++)
      af[mt] = *(const bf16x8*)(sA + ((wm * 64 + mt * 16 + l16) << 5) + (quad << 3));
    #pragma unroll
    for (int nt = 0; nt < 4; nt++)
      bfr[nt] = *(const bf16x8*)(sB + ((wn * 64 + nt * 16 + l16) << 5) + (quad << 3));
    #pragma unroll
    for (int mt = 0; mt < 4; mt++)
      #pragma unroll
      for (int nt = 0; nt < 4; nt++)
        acc[mt][nt] = __builtin_amdgcn_mfma_f32_16x16x32_bf16(af[mt], bfr[nt], acc[mt][nt], 0, 0, 0);
    __syncthreads();
  }

  float bcol[4];
  #pragma unroll
  for (int nt = 0; nt < 4; nt++) bcol[nt] = bias[tileN + wn * 64 + nt * 16 + l16];

  #pragma unroll
  for (int mt = 0; mt < 4; mt++) {
    #pragma unroll
    for (int r = 0; r < 4; r++) {
      long row = tileM + wm * 64 + mt * 16 + quad * 4 + r;
      if (MODE == 0) {
        __bf16* orow = outb + row * (long)N;
        #pragma unroll
        for (int nt = 0; nt < 4; nt++)
          orow[tileN + wn * 64 + nt * 16 + l16] = (__bf16)(acc[mt][nt][r] + bcol[nt]);
      } else if (MODE == 1) {
        if (row < MREAL) {
          int r32 = (int)row;
          int win = r32 / NTOK, t = r32 % NTOK;
          int rem = win % 100;
          int pr = (rem / 10) * 7 + t / 7;
          int pc = (rem % 10) * 7 + t % 7;
          if (pr < 64 && pc < 64) {
            long po = ((long)(win / 100) * 4096 + pr * 64 + pc) * DIM_;
            #pragma unroll
            for (int nt = 0; nt < 4; nt++) {
              long col = tileN + wn * 64 + nt * 16 + l16;
              outf[po + col] = res[po + col] + acc[mt][nt][r] + bcol[nt];
            }
          }
        }
      } else if (MODE == 2) {
        __bf16* orow = outb + row * (long)N;
        #pragma unroll
        for (int nt = 0; nt < 4; nt++) {
          float v = acc[mt][nt][r] + bcol[nt];
          orow[tileN + wn * 64 + nt * 16 + l16] = (__bf16)(0.5f * v * (1.f + erff(v * 0.70710678118654752f)));
        }
      } else {
        float* orow = outf + row * (long)N;
        const float* rrow = res + row * (long)N;
        #pragma unroll
        for (int nt = 0; nt < 4; nt++) {
          long col = tileN + wn * 64 + nt * 16 + l16;
          orow[col] = acc[mt][nt][r] + bcol[nt] + rrow[col];
        }
      }
    }
  }
}

// ---------------------------------------------------------------------------
extern "C" void kernel_launch(void* const* d_in, const int* in_sizes, int n_in,
                              void* d_out, int out_size, void* d_ws, size_t ws_size,
                              hipStream_t stream) {
  const float* x       = (const float*)d_in[0];
  const float* ln1_g   = (const float*)d_in[1];
  const float* ln1_b   = (const float*)d_in[2];
  const float* qkv_w   = (const float*)d_in[3];
  const float* qkv_b   = (const float*)d_in[4];
  const float* proj_w  = (const float*)d_in[5];
  const float* proj_b  = (const float*)d_in[6];
  const float* attn_b  = (const float*)d_in[7];
  const float* conv_w  = (const float*)d_in[8];
  const float* bn_g    = (const float*)d_in[9];
  const float* bn_b    = (const float*)d_in[10];
  const float* bn_mean = (const float*)d_in[11];
  const float* bn_var  = (const float*)d_in[12];
  const float* ln2_g   = (const float*)d_in[13];
  const float* ln2_b   = (const float*)d_in[14];
  const float* fc1_w   = (const float*)d_in[15];
  const float* fc1_b   = (const float*)d_in[16];
  const float* fc2_w   = (const float*)d_in[17];
  const float* fc2_b   = (const float*)d_in[18];

  // workspace layout (aliasing; ~130 MB total):
  char* p = (char*)d_ws;
  __bf16* WQKV = (__bf16*)p;  p += 884736;     // 1152x384
  __bf16* WPROJ = (__bf16*)p; p += 294912;     // 384x384
  __bf16* WFC1 = (__bf16*)p;  p += 1179648;    // 1536x384
  __bf16* WFC2 = (__bf16*)p;  p += 1179648;    // 384x1536
  float*  WCONV = (float*)p;  p += 13824;      // 9x384
  char* region = p;           p += 75694080;
  float* X1 = (float*)p;      p += 25165824;
  float* X2 = (float*)p;      p += 25165824;
  __bf16* XN   = (__bf16*)region;                 // 19712x384 (dead after QKV gemm)
  float*  BM   = (float*)region;                  // 12x64x64 bias table (aliases XN)
  __bf16* QKVB = (__bf16*)(region + 15138816);    // 19712x1152
  __bf16* OBUF = (__bf16*)(region + 60555264);    // 19712x384
  __bf16* XLN2 = (__bf16*)region;                 // 16384x384  (aliases XN/BM, dead)
  __bf16* H1   = (__bf16*)(region + 15138816);    // 16384x1536 (aliases QKVB+OBUF, dead)
  float* OUT = (float*)d_out;

  transpose_cast<<<(442368 + 255) / 256, 256, 0, stream>>>(qkv_w, WQKV, DIM_, QKVD);
  transpose_cast<<<(147456 + 255) / 256, 256, 0, stream>>>(proj_w, WPROJ, DIM_, DIM_);
  transpose_cast<<<(589824 + 255) / 256, 256, 0, stream>>>(fc1_w, WFC1, DIM_, HIDD);
  transpose_cast<<<(589824 + 255) / 256, 256, 0, stream>>>(fc2_w, WFC2, HIDD, DIM_);
  convw_transpose<<<14, 256, 0, stream>>>(conv_w, WCONV);

  ln1_window<<<MPAD, 128, 0, stream>>>(x, ln1_g, ln1_b, XN);

  gemm_bf16_128<0><<<dim3(MPAD / 128, QKVD / 128), 256, 0, stream>>>(
      XN, WQKV, qkv_b, DIM_, QKVD, nullptr, QKVB, nullptr);

  // XN dead now; BM aliases it.
  bias_expand<<<192, 256, 0, stream>>>(attn_b, BM);

  attn_mfma<<<NWIN * 12, 64, 0, stream>>>(QKVB, BM, OBUF);

  gemm_bf16_128<1><<<dim3(MPAD / 128, DIM_ / 128), 256, 0, stream>>>(
      OBUF, WPROJ, proj_b, DIM_, DIM_, X1, nullptr, x);

  conv_bn_ln2<<<TOKENS / 4, 384, 0, stream>>>(X1, WCONV, bn_g, bn_b, bn_mean, bn_var,
                                              ln2_g, ln2_b, X2, XLN2);

  gemm_bf16_128<2><<<dim3(TOKENS / 128, HIDD / 128), 256, 0, stream>>>(
      XLN2, WFC1, fc1_b, DIM_, HIDD, nullptr, H1, nullptr);

  gemm_bf16_128<3><<<dim3(TOKENS / 128, DIM_ / 128), 256, 0, stream>>>(
      H1, WFC2, fc2_b, HIDD, DIM_, OUT, nullptr, X2);
}

// Round 4
// 328.572 us; speedup vs baseline: 1.2899x; 1.0053x over previous
//
#include <hip/hip_runtime.h>
#include <cstdint>

// ---------------------------------------------------------------------------
// TinyViT block on gfx950. Round 4: fc1 epilogue GELU via sigmoid form
// (v/(1+e^-t), ~8 VALU ops) replacing erff (~40 ops x 64 elems/lane).
// Everything else unchanged from round 3 (verified).
// ---------------------------------------------------------------------------

typedef __bf16 bf16x8 __attribute__((ext_vector_type(8)));
typedef __bf16 bf16x4 __attribute__((ext_vector_type(4)));
typedef float  f32x4  __attribute__((ext_vector_type(4)));

#define DIM_    384
#define QKVD    1152
#define HIDD    1536
#define NTOK    49
#define NWIN    400
#define MPAD    19712     /* 154*128 */
#define MREAL   19600
#define TOKENS  16384     /* 4*4096 */
#define SCALE_  0.17677669529663689f
#define EPS_    1e-5f

__device__ __forceinline__ void gload_lds16(const void* g, void* l) {
  __builtin_amdgcn_global_load_lds(
      (__attribute__((address_space(1))) void*)g,
      (__attribute__((address_space(3))) void*)l, 16, 0, 0);
}

// tanh-form GELU: 0.5v(1+tanh(c(v+0.044715v^3))) == v * sigmoid(2c(v+0.044715v^3))
__device__ __forceinline__ float gelu_fast(float v) {
  float t2 = v * (1.5957691216057308f + 0.07135481627f * v * v);
  return v / (1.f + __expf(-t2));
}

// ---------------------------------------------------------------------------
// Weight transpose + cast: dst[n*K+k] = bf16(src[k*N+n])   (K x N -> N x K)
// ---------------------------------------------------------------------------
__global__ void transpose_cast(const float* __restrict__ src, __bf16* __restrict__ dst,
                               int K, int N) {
  long id = (long)blockIdx.x * 256 + threadIdx.x;
  if (id >= (long)K * N) return;
  int  k = (int)(id % K);
  long n = id / K;
  dst[n * K + k] = (__bf16)src[(long)k * N + n];
}

// conv_w [384][9] -> wT [9][384] (float, for float4 tap loads)
__global__ void convw_transpose(const float* __restrict__ w, float* __restrict__ wT) {
  int id = blockIdx.x * 256 + threadIdx.x;
  if (id >= 3456) return;
  int ch = id / 9, k = id % 9;
  wT[k * 384 + ch] = w[id];
}

// ---------------------------------------------------------------------------
// Expand attn_bias[12][49] -> bm[12][64][64] fp32, column-mask baked in.
// ---------------------------------------------------------------------------
__global__ void bias_expand(const float* __restrict__ ab, float* __restrict__ bm) {
  int id = blockIdx.x * 256 + threadIdx.x;           // 12*64*64 = 49152
  int h = id >> 12, q = (id >> 6) & 63, kk = id & 63;
  float v;
  if (kk >= NTOK)      v = -1e30f;
  else if (q >= NTOK)  v = 0.f;
  else {
    int idx = abs(q / 7 - kk / 7) * 7 + abs(q % 7 - kk % 7);
    v = ab[h * NTOK + idx];
  }
  bm[id] = v;
}

// ---------------------------------------------------------------------------
// LN1 + window partition. Block = one padded-window token (19712), 128 thr.
// ---------------------------------------------------------------------------
__global__ void ln1_window(const float* __restrict__ x, const float* __restrict__ gam,
                           const float* __restrict__ bet, __bf16* __restrict__ xn) {
  int t   = blockIdx.x;
  int tid = threadIdx.x;
  __bf16* orow = xn + (long)t * DIM_;
  if (t >= MREAL) {
    for (int i = tid; i < DIM_; i += 128) orow[i] = (__bf16)0.f;
    return;
  }
  int win = t / NTOK, tt = t % NTOK;
  int bb = win / 100, rem = win % 100;
  int r = (rem / 10) * 7 + tt / 7;
  int c = (rem % 10) * 7 + tt % 7;
  if (r >= 64 || c >= 64) {
    for (int i = tid; i < DIM_; i += 128) orow[i] = (__bf16)bet[i];
    return;
  }
  const float* xr = x + ((long)bb * 4096 + r * 64 + c) * DIM_;
  float v0 = xr[tid], v1 = xr[tid + 128], v2 = xr[tid + 256];
  float s = v0 + v1 + v2, s2 = v0 * v0 + v1 * v1 + v2 * v2;
  for (int off = 32; off; off >>= 1) { s += __shfl_down(s, off); s2 += __shfl_down(s2, off); }
  __shared__ float red[4];
  if ((tid & 63) == 0) { red[tid >> 6] = s; red[2 + (tid >> 6)] = s2; }
  __syncthreads();
  float S = red[0] + red[1], S2 = red[2] + red[3];
  float m  = S * (1.f / DIM_);
  float rs = rsqrtf(S2 * (1.f / DIM_) - m * m + EPS_);
  orow[tid]       = (__bf16)((v0 - m) * rs * gam[tid]       + bet[tid]);
  orow[tid + 128] = (__bf16)((v1 - m) * rs * gam[tid + 128] + bet[tid + 128]);
  orow[tid + 256] = (__bf16)((v2 - m) * rs * gam[tid + 256] + bet[tid + 256]);
}

// ---------------------------------------------------------------------------
// Fused depthwise 3x3 conv + BN + LN2. Block = 4 pixels x 96 lanes (384 thr).
// ---------------------------------------------------------------------------
__global__ __launch_bounds__(384) void conv_bn_ln2(
    const float* __restrict__ x1, const float* __restrict__ wT,
    const float* __restrict__ bng, const float* __restrict__ bnb,
    const float* __restrict__ mean, const float* __restrict__ var,
    const float* __restrict__ g2, const float* __restrict__ b2,
    float* __restrict__ x2, __bf16* __restrict__ xln2) {
  int tid = threadIdx.x;
  int p = tid / 96, g = tid % 96;
  int pix = blockIdx.x * 4 + p;            // 0..16383
  int bb = pix >> 12, rc = pix & 4095;
  int r = rc >> 6, c = rc & 63;
  int ch = g << 2;

  f32x4 acc = (f32x4){0.f, 0.f, 0.f, 0.f};
  #pragma unroll
  for (int dr = -1; dr <= 1; dr++) {
    int rr = r + dr;
    if (rr < 0 || rr >= 64) continue;
    #pragma unroll
    for (int dc = -1; dc <= 1; dc++) {
      int cc = c + dc;
      if (cc < 0 || cc >= 64) continue;
      f32x4 xv = *(const f32x4*)(x1 + ((long)bb * 4096 + rr * 64 + cc) * DIM_ + ch);
      f32x4 wv = *(const f32x4*)(wT + ((dr + 1) * 3 + (dc + 1)) * DIM_ + ch);
      acc += xv * wv;
    }
  }

  f32x4 gv = *(const f32x4*)(bng + ch);
  f32x4 vv = *(const f32x4*)(var + ch);
  f32x4 mv = *(const f32x4*)(mean + ch);
  f32x4 bv = *(const f32x4*)(bnb + ch);
  f32x4 y;
  #pragma unroll
  for (int j = 0; j < 4; j++) {
    float sc = gv[j] * rsqrtf(vv[j] + EPS_);
    y[j] = acc[j] * sc + (bv[j] - mv[j] * sc);
  }
  *(f32x4*)(x2 + (long)pix * DIM_ + ch) = y;

  __shared__ float pS[4][96], pS2[4][96], mS[4], rS[4];
  pS[p][g]  = y[0] + y[1] + y[2] + y[3];
  pS2[p][g] = y[0] * y[0] + y[1] * y[1] + y[2] * y[2] + y[3] * y[3];
  __syncthreads();
  if (g < 32) {
    float a  = pS[p][g]  + pS[p][g + 32]  + pS[p][g + 64];
    float a2 = pS2[p][g] + pS2[p][g + 32] + pS2[p][g + 64];
    #pragma unroll
    for (int off = 1; off < 32; off <<= 1) {
      a  += __shfl_xor(a, off);
      a2 += __shfl_xor(a2, off);
    }
    if (g == 0) {
      float m = a * (1.f / DIM_);
      mS[p] = m;
      rS[p] = rsqrtf(a2 * (1.f / DIM_) - m * m + EPS_);
    }
  }
  __syncthreads();
  float m = mS[p], rs = rS[p];
  f32x4 gg = *(const f32x4*)(g2 + ch);
  f32x4 b2v = *(const f32x4*)(b2 + ch);
  bf16x4 ov;
  #pragma unroll
  for (int j = 0; j < 4; j++) ov[j] = (__bf16)((y[j] - m) * rs * gg[j] + b2v[j]);
  *(bf16x4*)(xln2 + (long)pix * DIM_ + ch) = ov;
}

// ---------------------------------------------------------------------------
// MFMA attention: one 64-thread block per (window, head). 4800 blocks.
// ---------------------------------------------------------------------------
__global__ __launch_bounds__(64) void attn_mfma(const __bf16* __restrict__ qkv,
                                                const float* __restrict__ bm,
                                                __bf16* __restrict__ o) {
  int blk = blockIdx.x;
  int win = blk / 12, h = blk % 12;
  int lane = threadIdx.x;
  int quad = lane >> 4, l16 = lane & 15;

  __shared__ __align__(16) __bf16 Vt[32][72];   // Vt[d][kk]
  __shared__ __align__(16) __bf16 P[64][72];    // P[q][kk]

  const __bf16* base = qkv + (long)win * NTOK * QKVD + h * 96;

  bf16x8 qf[4], kf[4];
  #pragma unroll
  for (int t = 0; t < 4; t++) {
    const __bf16* rp = base + (long)(t * 16 + l16) * QKVD + quad * 8;
    qf[t] = *(const bf16x8*)(rp);
    kf[t] = *(const bf16x8*)(rp + 32);
  }
  {
    const __bf16* vp = base + (long)lane * QKVD + 64;
    bf16x8 vv[4];
    #pragma unroll
    for (int i = 0; i < 4; i++) vv[i] = *(const bf16x8*)(vp + i * 8);
    #pragma unroll
    for (int i = 0; i < 4; i++)
      #pragma unroll
      for (int j = 0; j < 8; j++) Vt[i * 8 + j][lane] = vv[i][j];
  }

  f32x4 S[4][4];
  #pragma unroll
  for (int i = 0; i < 4; i++)
    #pragma unroll
    for (int j = 0; j < 4; j++) S[i][j] = (f32x4){0.f, 0.f, 0.f, 0.f};
  #pragma unroll
  for (int mt = 0; mt < 4; mt++)
    #pragma unroll
    for (int nt = 0; nt < 4; nt++)
      S[mt][nt] = __builtin_amdgcn_mfma_f32_16x16x32_bf16(qf[mt], kf[nt], S[mt][nt], 0, 0, 0);

  const float* bmh = bm + h * 4096;
  #pragma unroll
  for (int mt = 0; mt < 4; mt++)
    #pragma unroll
    for (int r = 0; r < 4; r++) {
      int q = mt * 16 + quad * 4 + r;
      #pragma unroll
      for (int nt = 0; nt < 4; nt++)
        S[mt][nt][r] = S[mt][nt][r] * SCALE_ + bmh[q * 64 + nt * 16 + l16];
    }

  #pragma unroll
  for (int mt = 0; mt < 4; mt++)
    #pragma unroll
    for (int r = 0; r < 4; r++) {
      float mx = fmaxf(fmaxf(S[mt][0][r], S[mt][1][r]), fmaxf(S[mt][2][r], S[mt][3][r]));
      #pragma unroll
      for (int off = 1; off < 16; off <<= 1) mx = fmaxf(mx, __shfl_xor(mx, off));
      float sum = 0.f;
      #pragma unroll
      for (int nt = 0; nt < 4; nt++) {
        float e = __expf(S[mt][nt][r] - mx);
        S[mt][nt][r] = e;
        sum += e;
      }
      #pragma unroll
      for (int off = 1; off < 16; off <<= 1) sum += __shfl_xor(sum, off);
      float inv = 1.f / sum;
      #pragma unroll
      for (int nt = 0; nt < 4; nt++) S[mt][nt][r] *= inv;
    }

  #pragma unroll
  for (int mt = 0; mt < 4; mt++)
    #pragma unroll
    for (int r = 0; r < 4; r++) {
      int q = mt * 16 + quad * 4 + r;
      #pragma unroll
      for (int nt = 0; nt < 4; nt++)
        P[q][nt * 16 + l16] = (__bf16)S[mt][nt][r];
    }
  __syncthreads();

  f32x4 O[4][2];
  #pragma unroll
  for (int i = 0; i < 4; i++)
    #pragma unroll
    for (int j = 0; j < 2; j++) O[i][j] = (f32x4){0.f, 0.f, 0.f, 0.f};
  #pragma unroll
  for (int kt = 0; kt < 2; kt++) {
    bf16x8 pf[4], vf[2];
    #pragma unroll
    for (int mt = 0; mt < 4; mt++)
      pf[mt] = *(const bf16x8*)(&P[mt * 16 + l16][kt * 32 + quad * 8]);
    #pragma unroll
    for (int nt = 0; nt < 2; nt++)
      vf[nt] = *(const bf16x8*)(&Vt[nt * 16 + l16][kt * 32 + quad * 8]);
    #pragma unroll
    for (int mt = 0; mt < 4; mt++)
      #pragma unroll
      for (int nt = 0; nt < 2; nt++)
        O[mt][nt] = __builtin_amdgcn_mfma_f32_16x16x32_bf16(pf[mt], vf[nt], O[mt][nt], 0, 0, 0);
  }

  __bf16* ob = o + (long)win * NTOK * DIM_ + h * 32;
  #pragma unroll
  for (int mt = 0; mt < 4; mt++)
    #pragma unroll
    for (int r = 0; r < 4; r++) {
      int q = mt * 16 + quad * 4 + r;
      if (q < NTOK) {
        #pragma unroll
        for (int nt = 0; nt < 2; nt++)
          ob[(long)q * DIM_ + nt * 16 + l16] = (__bf16)O[mt][nt][r];
      }
    }
}

// ---------------------------------------------------------------------------
// bf16 MFMA GEMM, C(MxN) = A(MxK) @ Bt(NxK)^T, 128x128 tile, 4 waves (2x2),
// BK=32, global_load_lds(16B) staging, fused epilogues.
// MODE 0: qkv   -> bf16 out = acc + bias
// MODE 1: proj  -> window-reverse scatter: X1 = x + acc + bias (valid pixels)
// MODE 2: fc1   -> bf16 out = gelu_fast(acc + bias)
// MODE 3: fc2   -> f32 out = acc + bias + res
// ---------------------------------------------------------------------------
template <int MODE>
__global__ void __launch_bounds__(256)
gemm_bf16_128(const __bf16* __restrict__ A, const __bf16* __restrict__ Bt,
              const float* __restrict__ bias, int K, int N,
              float* __restrict__ outf, __bf16* __restrict__ outb,
              const float* __restrict__ res) {
  __shared__ __align__(16) __bf16 sA[128 * 32];
  __shared__ __align__(16) __bf16 sB[128 * 32];
  int tid = threadIdx.x, lane = tid & 63, wid = tid >> 6;
  int wm = wid >> 1, wn = wid & 1;
  int quad = lane >> 4, l16 = lane & 15;
  long tileM = (long)blockIdx.x * 128;
  long tileN = (long)blockIdx.y * 128;

  f32x4 acc[4][4];
  #pragma unroll
  for (int i = 0; i < 4; i++)
    #pragma unroll
    for (int j = 0; j < 4; j++) acc[i][j] = (f32x4){0.f, 0.f, 0.f, 0.f};

  int rA = wid * 16 + (lane >> 2);
  const __bf16* gA = A  + (tileM + rA) * (long)K + ((lane & 3) << 3);
  const __bf16* gB = Bt + (tileN + rA) * (long)K + ((lane & 3) << 3);
  __bf16* lA0 = sA + (wid << 9);
  __bf16* lA1 = sA + ((wid + 4) << 9);
  __bf16* lB0 = sB + (wid << 9);
  __bf16* lB1 = sB + ((wid + 4) << 9);
  const long rowskip = 64 * (long)K;

  for (int k0 = 0; k0 < K; k0 += 32) {
    gload_lds16(gA + k0,           lA0);
    gload_lds16(gA + k0 + rowskip, lA1);
    gload_lds16(gB + k0,           lB0);
    gload_lds16(gB + k0 + rowskip, lB1);
    __syncthreads();
    bf16x8 af[4], bfr[4];
    #pragma unroll
    for (int mt = 0; mt < 4; mt++)
      af[mt] = *(const bf16x8*)(sA + ((wm * 64 + mt * 16 + l16) << 5) + (quad << 3));
    #pragma unroll
    for (int nt = 0; nt < 4; nt++)
      bfr[nt] = *(const bf16x8*)(sB + ((wn * 64 + nt * 16 + l16) << 5) + (quad << 3));
    #pragma unroll
    for (int mt = 0; mt < 4; mt++)
      #pragma unroll
      for (int nt = 0; nt < 4; nt++)
        acc[mt][nt] = __builtin_amdgcn_mfma_f32_16x16x32_bf16(af[mt], bfr[nt], acc[mt][nt], 0, 0, 0);
    __syncthreads();
  }

  float bcol[4];
  #pragma unroll
  for (int nt = 0; nt < 4; nt++) bcol[nt] = bias[tileN + wn * 64 + nt * 16 + l16];

  #pragma unroll
  for (int mt = 0; mt < 4; mt++) {
    #pragma unroll
    for (int r = 0; r < 4; r++) {
      long row = tileM + wm * 64 + mt * 16 + quad * 4 + r;
      if (MODE == 0) {
        __bf16* orow = outb + row * (long)N;
        #pragma unroll
        for (int nt = 0; nt < 4; nt++)
          orow[tileN + wn * 64 + nt * 16 + l16] = (__bf16)(acc[mt][nt][r] + bcol[nt]);
      } else if (MODE == 1) {
        if (row < MREAL) {
          int r32 = (int)row;
          int win = r32 / NTOK, t = r32 % NTOK;
          int rem = win % 100;
          int pr = (rem / 10) * 7 + t / 7;
          int pc = (rem % 10) * 7 + t % 7;
          if (pr < 64 && pc < 64) {
            long po = ((long)(win / 100) * 4096 + pr * 64 + pc) * DIM_;
            #pragma unroll
            for (int nt = 0; nt < 4; nt++) {
              long col = tileN + wn * 64 + nt * 16 + l16;
              outf[po + col] = res[po + col] + acc[mt][nt][r] + bcol[nt];
            }
          }
        }
      } else if (MODE == 2) {
        __bf16* orow = outb + row * (long)N;
        #pragma unroll
        for (int nt = 0; nt < 4; nt++) {
          float v = acc[mt][nt][r] + bcol[nt];
          orow[tileN + wn * 64 + nt * 16 + l16] = (__bf16)gelu_fast(v);
        }
      } else {
        float* orow = outf + row * (long)N;
        const float* rrow = res + row * (long)N;
        #pragma unroll
        for (int nt = 0; nt < 4; nt++) {
          long col = tileN + wn * 64 + nt * 16 + l16;
          orow[col] = acc[mt][nt][r] + bcol[nt] + rrow[col];
        }
      }
    }
  }
}

// ---------------------------------------------------------------------------
extern "C" void kernel_launch(void* const* d_in, const int* in_sizes, int n_in,
                              void* d_out, int out_size, void* d_ws, size_t ws_size,
                              hipStream_t stream) {
  const float* x       = (const float*)d_in[0];
  const float* ln1_g   = (const float*)d_in[1];
  const float* ln1_b   = (const float*)d_in[2];
  const float* qkv_w   = (const float*)d_in[3];
  const float* qkv_b   = (const float*)d_in[4];
  const float* proj_w  = (const float*)d_in[5];
  const float* proj_b  = (const float*)d_in[6];
  const float* attn_b  = (const float*)d_in[7];
  const float* conv_w  = (const float*)d_in[8];
  const float* bn_g    = (const float*)d_in[9];
  const float* bn_b    = (const float*)d_in[10];
  const float* bn_mean = (const float*)d_in[11];
  const float* bn_var  = (const float*)d_in[12];
  const float* ln2_g   = (const float*)d_in[13];
  const float* ln2_b   = (const float*)d_in[14];
  const float* fc1_w   = (const float*)d_in[15];
  const float* fc1_b   = (const float*)d_in[16];
  const float* fc2_w   = (const float*)d_in[17];
  const float* fc2_b   = (const float*)d_in[18];

  // workspace layout (aliasing; ~130 MB total):
  char* p = (char*)d_ws;
  __bf16* WQKV = (__bf16*)p;  p += 884736;     // 1152x384
  __bf16* WPROJ = (__bf16*)p; p += 294912;     // 384x384
  __bf16* WFC1 = (__bf16*)p;  p += 1179648;    // 1536x384
  __bf16* WFC2 = (__bf16*)p;  p += 1179648;    // 384x1536
  float*  WCONV = (float*)p;  p += 13824;      // 9x384
  char* region = p;           p += 75694080;
  float* X1 = (float*)p;      p += 25165824;
  float* X2 = (float*)p;      p += 25165824;
  __bf16* XN   = (__bf16*)region;                 // 19712x384 (dead after QKV gemm)
  float*  BM   = (float*)region;                  // 12x64x64 bias table (aliases XN)
  __bf16* QKVB = (__bf16*)(region + 15138816);    // 19712x1152
  __bf16* OBUF = (__bf16*)(region + 60555264);    // 19712x384
  __bf16* XLN2 = (__bf16*)region;                 // 16384x384  (aliases XN/BM, dead)
  __bf16* H1   = (__bf16*)(region + 15138816);    // 16384x1536 (aliases QKVB+OBUF, dead)
  float* OUT = (float*)d_out;

  transpose_cast<<<(442368 + 255) / 256, 256, 0, stream>>>(qkv_w, WQKV, DIM_, QKVD);
  transpose_cast<<<(147456 + 255) / 256, 256, 0, stream>>>(proj_w, WPROJ, DIM_, DIM_);
  transpose_cast<<<(589824 + 255) / 256, 256, 0, stream>>>(fc1_w, WFC1, DIM_, HIDD);
  transpose_cast<<<(589824 + 255) / 256, 256, 0, stream>>>(fc2_w, WFC2, HIDD, DIM_);
  convw_transpose<<<14, 256, 0, stream>>>(conv_w, WCONV);

  ln1_window<<<MPAD, 128, 0, stream>>>(x, ln1_g, ln1_b, XN);

  gemm_bf16_128<0><<<dim3(MPAD / 128, QKVD / 128), 256, 0, stream>>>(
      XN, WQKV, qkv_b, DIM_, QKVD, nullptr, QKVB, nullptr);

  // XN dead now; BM aliases it.
  bias_expand<<<192, 256, 0, stream>>>(attn_b, BM);

  attn_mfma<<<NWIN * 12, 64, 0, stream>>>(QKVB, BM, OBUF);

  gemm_bf16_128<1><<<dim3(MPAD / 128, DIM_ / 128), 256, 0, stream>>>(
      OBUF, WPROJ, proj_b, DIM_, DIM_, X1, nullptr, x);

  conv_bn_ln2<<<TOKENS / 4, 384, 0, stream>>>(X1, WCONV, bn_g, bn_b, bn_mean, bn_var,
                                              ln2_g, ln2_b, X2, XLN2);

  gemm_bf16_128<2><<<dim3(TOKENS / 128, HIDD / 128), 256, 0, stream>>>(
      XLN2, WFC1, fc1_b, DIM_, HIDD, nullptr, H1, nullptr);

  gemm_bf16_128<3><<<dim3(TOKENS / 128, DIM_ / 128), 256, 0, stream>>>(
      H1, WFC2, fc2_b, HIDD, DIM_, OUT, nullptr, X2);
}

// Round 5
// 325.524 us; speedup vs baseline: 1.3020x; 1.0094x over previous
//
#include <hip/hip_runtime.h>
#include <cstdint>

// ---------------------------------------------------------------------------
// TinyViT block on gfx950. Round 5: TN=64 GEMM variant for narrow-N GEMMs
// (proj N=384, fc2 N=384) -> 924/768 blocks instead of 462/384, fixing the
// grid-limited occupancy (13.8%) seen in round 4. qkv/fc1 keep TN=128.
// ---------------------------------------------------------------------------

typedef __bf16 bf16x8 __attribute__((ext_vector_type(8)));
typedef __bf16 bf16x4 __attribute__((ext_vector_type(4)));
typedef float  f32x4  __attribute__((ext_vector_type(4)));

#define DIM_    384
#define QKVD    1152
#define HIDD    1536
#define NTOK    49
#define NWIN    400
#define MPAD    19712     /* 154*128 */
#define MREAL   19600
#define TOKENS  16384     /* 4*4096 */
#define SCALE_  0.17677669529663689f
#define EPS_    1e-5f

__device__ __forceinline__ void gload_lds16(const void* g, void* l) {
  __builtin_amdgcn_global_load_lds(
      (__attribute__((address_space(1))) void*)g,
      (__attribute__((address_space(3))) void*)l, 16, 0, 0);
}

// tanh-form GELU: 0.5v(1+tanh(c(v+0.044715v^3))) == v * sigmoid(2c(v+0.044715v^3))
__device__ __forceinline__ float gelu_fast(float v) {
  float t2 = v * (1.5957691216057308f + 0.07135481627f * v * v);
  return v / (1.f + __expf(-t2));
}

// ---------------------------------------------------------------------------
// Weight transpose + cast: dst[n*K+k] = bf16(src[k*N+n])   (K x N -> N x K)
// ---------------------------------------------------------------------------
__global__ void transpose_cast(const float* __restrict__ src, __bf16* __restrict__ dst,
                               int K, int N) {
  long id = (long)blockIdx.x * 256 + threadIdx.x;
  if (id >= (long)K * N) return;
  int  k = (int)(id % K);
  long n = id / K;
  dst[n * K + k] = (__bf16)src[(long)k * N + n];
}

// conv_w [384][9] -> wT [9][384] (float, for float4 tap loads)
__global__ void convw_transpose(const float* __restrict__ w, float* __restrict__ wT) {
  int id = blockIdx.x * 256 + threadIdx.x;
  if (id >= 3456) return;
  int ch = id / 9, k = id % 9;
  wT[k * 384 + ch] = w[id];
}

// ---------------------------------------------------------------------------
// Expand attn_bias[12][49] -> bm[12][64][64] fp32, column-mask baked in.
// ---------------------------------------------------------------------------
__global__ void bias_expand(const float* __restrict__ ab, float* __restrict__ bm) {
  int id = blockIdx.x * 256 + threadIdx.x;           // 12*64*64 = 49152
  int h = id >> 12, q = (id >> 6) & 63, kk = id & 63;
  float v;
  if (kk >= NTOK)      v = -1e30f;
  else if (q >= NTOK)  v = 0.f;
  else {
    int idx = abs(q / 7 - kk / 7) * 7 + abs(q % 7 - kk % 7);
    v = ab[h * NTOK + idx];
  }
  bm[id] = v;
}

// ---------------------------------------------------------------------------
// LN1 + window partition. Block = one padded-window token (19712), 128 thr.
// ---------------------------------------------------------------------------
__global__ void ln1_window(const float* __restrict__ x, const float* __restrict__ gam,
                           const float* __restrict__ bet, __bf16* __restrict__ xn) {
  int t   = blockIdx.x;
  int tid = threadIdx.x;
  __bf16* orow = xn + (long)t * DIM_;
  if (t >= MREAL) {
    for (int i = tid; i < DIM_; i += 128) orow[i] = (__bf16)0.f;
    return;
  }
  int win = t / NTOK, tt = t % NTOK;
  int bb = win / 100, rem = win % 100;
  int r = (rem / 10) * 7 + tt / 7;
  int c = (rem % 10) * 7 + tt % 7;
  if (r >= 64 || c >= 64) {
    for (int i = tid; i < DIM_; i += 128) orow[i] = (__bf16)bet[i];
    return;
  }
  const float* xr = x + ((long)bb * 4096 + r * 64 + c) * DIM_;
  float v0 = xr[tid], v1 = xr[tid + 128], v2 = xr[tid + 256];
  float s = v0 + v1 + v2, s2 = v0 * v0 + v1 * v1 + v2 * v2;
  for (int off = 32; off; off >>= 1) { s += __shfl_down(s, off); s2 += __shfl_down(s2, off); }
  __shared__ float red[4];
  if ((tid & 63) == 0) { red[tid >> 6] = s; red[2 + (tid >> 6)] = s2; }
  __syncthreads();
  float S = red[0] + red[1], S2 = red[2] + red[3];
  float m  = S * (1.f / DIM_);
  float rs = rsqrtf(S2 * (1.f / DIM_) - m * m + EPS_);
  orow[tid]       = (__bf16)((v0 - m) * rs * gam[tid]       + bet[tid]);
  orow[tid + 128] = (__bf16)((v1 - m) * rs * gam[tid + 128] + bet[tid + 128]);
  orow[tid + 256] = (__bf16)((v2 - m) * rs * gam[tid + 256] + bet[tid + 256]);
}

// ---------------------------------------------------------------------------
// Fused depthwise 3x3 conv + BN + LN2. Block = 4 pixels x 96 lanes (384 thr).
// ---------------------------------------------------------------------------
__global__ __launch_bounds__(384) void conv_bn_ln2(
    const float* __restrict__ x1, const float* __restrict__ wT,
    const float* __restrict__ bng, const float* __restrict__ bnb,
    const float* __restrict__ mean, const float* __restrict__ var,
    const float* __restrict__ g2, const float* __restrict__ b2,
    float* __restrict__ x2, __bf16* __restrict__ xln2) {
  int tid = threadIdx.x;
  int p = tid / 96, g = tid % 96;
  int pix = blockIdx.x * 4 + p;            // 0..16383
  int bb = pix >> 12, rc = pix & 4095;
  int r = rc >> 6, c = rc & 63;
  int ch = g << 2;

  f32x4 acc = (f32x4){0.f, 0.f, 0.f, 0.f};
  #pragma unroll
  for (int dr = -1; dr <= 1; dr++) {
    int rr = r + dr;
    if (rr < 0 || rr >= 64) continue;
    #pragma unroll
    for (int dc = -1; dc <= 1; dc++) {
      int cc = c + dc;
      if (cc < 0 || cc >= 64) continue;
      f32x4 xv = *(const f32x4*)(x1 + ((long)bb * 4096 + rr * 64 + cc) * DIM_ + ch);
      f32x4 wv = *(const f32x4*)(wT + ((dr + 1) * 3 + (dc + 1)) * DIM_ + ch);
      acc += xv * wv;
    }
  }

  f32x4 gv = *(const f32x4*)(bng + ch);
  f32x4 vv = *(const f32x4*)(var + ch);
  f32x4 mv = *(const f32x4*)(mean + ch);
  f32x4 bv = *(const f32x4*)(bnb + ch);
  f32x4 y;
  #pragma unroll
  for (int j = 0; j < 4; j++) {
    float sc = gv[j] * rsqrtf(vv[j] + EPS_);
    y[j] = acc[j] * sc + (bv[j] - mv[j] * sc);
  }
  *(f32x4*)(x2 + (long)pix * DIM_ + ch) = y;

  __shared__ float pS[4][96], pS2[4][96], mS[4], rS[4];
  pS[p][g]  = y[0] + y[1] + y[2] + y[3];
  pS2[p][g] = y[0] * y[0] + y[1] * y[1] + y[2] * y[2] + y[3] * y[3];
  __syncthreads();
  if (g < 32) {
    float a  = pS[p][g]  + pS[p][g + 32]  + pS[p][g + 64];
    float a2 = pS2[p][g] + pS2[p][g + 32] + pS2[p][g + 64];
    #pragma unroll
    for (int off = 1; off < 32; off <<= 1) {
      a  += __shfl_xor(a, off);
      a2 += __shfl_xor(a2, off);
    }
    if (g == 0) {
      float m = a * (1.f / DIM_);
      mS[p] = m;
      rS[p] = rsqrtf(a2 * (1.f / DIM_) - m * m + EPS_);
    }
  }
  __syncthreads();
  float m = mS[p], rs = rS[p];
  f32x4 gg = *(const f32x4*)(g2 + ch);
  f32x4 b2v = *(const f32x4*)(b2 + ch);
  bf16x4 ov;
  #pragma unroll
  for (int j = 0; j < 4; j++) ov[j] = (__bf16)((y[j] - m) * rs * gg[j] + b2v[j]);
  *(bf16x4*)(xln2 + (long)pix * DIM_ + ch) = ov;
}

// ---------------------------------------------------------------------------
// MFMA attention: one 64-thread block per (window, head). 4800 blocks.
// ---------------------------------------------------------------------------
__global__ __launch_bounds__(64) void attn_mfma(const __bf16* __restrict__ qkv,
                                                const float* __restrict__ bm,
                                                __bf16* __restrict__ o) {
  int blk = blockIdx.x;
  int win = blk / 12, h = blk % 12;
  int lane = threadIdx.x;
  int quad = lane >> 4, l16 = lane & 15;

  __shared__ __align__(16) __bf16 Vt[32][72];   // Vt[d][kk]
  __shared__ __align__(16) __bf16 P[64][72];    // P[q][kk]

  const __bf16* base = qkv + (long)win * NTOK * QKVD + h * 96;

  bf16x8 qf[4], kf[4];
  #pragma unroll
  for (int t = 0; t < 4; t++) {
    const __bf16* rp = base + (long)(t * 16 + l16) * QKVD + quad * 8;
    qf[t] = *(const bf16x8*)(rp);
    kf[t] = *(const bf16x8*)(rp + 32);
  }
  {
    const __bf16* vp = base + (long)lane * QKVD + 64;
    bf16x8 vv[4];
    #pragma unroll
    for (int i = 0; i < 4; i++) vv[i] = *(const bf16x8*)(vp + i * 8);
    #pragma unroll
    for (int i = 0; i < 4; i++)
      #pragma unroll
      for (int j = 0; j < 8; j++) Vt[i * 8 + j][lane] = vv[i][j];
  }

  f32x4 S[4][4];
  #pragma unroll
  for (int i = 0; i < 4; i++)
    #pragma unroll
    for (int j = 0; j < 4; j++) S[i][j] = (f32x4){0.f, 0.f, 0.f, 0.f};
  #pragma unroll
  for (int mt = 0; mt < 4; mt++)
    #pragma unroll
    for (int nt = 0; nt < 4; nt++)
      S[mt][nt] = __builtin_amdgcn_mfma_f32_16x16x32_bf16(qf[mt], kf[nt], S[mt][nt], 0, 0, 0);

  const float* bmh = bm + h * 4096;
  #pragma unroll
  for (int mt = 0; mt < 4; mt++)
    #pragma unroll
    for (int r = 0; r < 4; r++) {
      int q = mt * 16 + quad * 4 + r;
      #pragma unroll
      for (int nt = 0; nt < 4; nt++)
        S[mt][nt][r] = S[mt][nt][r] * SCALE_ + bmh[q * 64 + nt * 16 + l16];
    }

  #pragma unroll
  for (int mt = 0; mt < 4; mt++)
    #pragma unroll
    for (int r = 0; r < 4; r++) {
      float mx = fmaxf(fmaxf(S[mt][0][r], S[mt][1][r]), fmaxf(S[mt][2][r], S[mt][3][r]));
      #pragma unroll
      for (int off = 1; off < 16; off <<= 1) mx = fmaxf(mx, __shfl_xor(mx, off));
      float sum = 0.f;
      #pragma unroll
      for (int nt = 0; nt < 4; nt++) {
        float e = __expf(S[mt][nt][r] - mx);
        S[mt][nt][r] = e;
        sum += e;
      }
      #pragma unroll
      for (int off = 1; off < 16; off <<= 1) sum += __shfl_xor(sum, off);
      float inv = 1.f / sum;
      #pragma unroll
      for (int nt = 0; nt < 4; nt++) S[mt][nt][r] *= inv;
    }

  #pragma unroll
  for (int mt = 0; mt < 4; mt++)
    #pragma unroll
    for (int r = 0; r < 4; r++) {
      int q = mt * 16 + quad * 4 + r;
      #pragma unroll
      for (int nt = 0; nt < 4; nt++)
        P[q][nt * 16 + l16] = (__bf16)S[mt][nt][r];
    }
  __syncthreads();

  f32x4 O[4][2];
  #pragma unroll
  for (int i = 0; i < 4; i++)
    #pragma unroll
    for (int j = 0; j < 2; j++) O[i][j] = (f32x4){0.f, 0.f, 0.f, 0.f};
  #pragma unroll
  for (int kt = 0; kt < 2; kt++) {
    bf16x8 pf[4], vf[2];
    #pragma unroll
    for (int mt = 0; mt < 4; mt++)
      pf[mt] = *(const bf16x8*)(&P[mt * 16 + l16][kt * 32 + quad * 8]);
    #pragma unroll
    for (int nt = 0; nt < 2; nt++)
      vf[nt] = *(const bf16x8*)(&Vt[nt * 16 + l16][kt * 32 + quad * 8]);
    #pragma unroll
    for (int mt = 0; mt < 4; mt++)
      #pragma unroll
      for (int nt = 0; nt < 2; nt++)
        O[mt][nt] = __builtin_amdgcn_mfma_f32_16x16x32_bf16(pf[mt], vf[nt], O[mt][nt], 0, 0, 0);
  }

  __bf16* ob = o + (long)win * NTOK * DIM_ + h * 32;
  #pragma unroll
  for (int mt = 0; mt < 4; mt++)
    #pragma unroll
    for (int r = 0; r < 4; r++) {
      int q = mt * 16 + quad * 4 + r;
      if (q < NTOK) {
        #pragma unroll
        for (int nt = 0; nt < 2; nt++)
          ob[(long)q * DIM_ + nt * 16 + l16] = (__bf16)O[mt][nt][r];
      }
    }
}

// ---------------------------------------------------------------------------
// bf16 MFMA GEMM, C(MxN) = A(MxK) @ Bt(NxK)^T. Tile 128 x TN (TN=128 or 64),
// 4 waves (2x2), BK=32, global_load_lds(16B) staging, fused epilogues.
// MODE 0: qkv   -> bf16 out = acc + bias
// MODE 1: proj  -> window-reverse scatter: X1 = x + acc + bias (valid pixels)
// MODE 2: fc1   -> bf16 out = gelu_fast(acc + bias)
// MODE 3: fc2   -> f32 out = acc + bias + res
// ---------------------------------------------------------------------------
template <int MODE, int TN>
__global__ void __launch_bounds__(256)
gemm_bf16(const __bf16* __restrict__ A, const __bf16* __restrict__ Bt,
          const float* __restrict__ bias, int K, int N,
          float* __restrict__ outf, __bf16* __restrict__ outb,
          const float* __restrict__ res) {
  constexpr int NT = TN / 32;                 // acc col-tiles per wave
  __shared__ __align__(16) __bf16 sA[128 * 32];
  __shared__ __align__(16) __bf16 sB[TN * 32];
  int tid = threadIdx.x, lane = tid & 63, wid = tid >> 6;
  int wm = wid >> 1, wn = wid & 1;
  int quad = lane >> 4, l16 = lane & 15;
  long tileM = (long)blockIdx.x * 128;
  long tileN = (long)blockIdx.y * TN;

  f32x4 acc[4][NT];
  #pragma unroll
  for (int i = 0; i < 4; i++)
    #pragma unroll
    for (int j = 0; j < NT; j++) acc[i][j] = (f32x4){0.f, 0.f, 0.f, 0.f};

  int rr = wid * 16 + (lane >> 2);
  const __bf16* gA = A  + (tileM + rr) * (long)K + ((lane & 3) << 3);
  const __bf16* gB = Bt + (tileN + rr) * (long)K + ((lane & 3) << 3);
  const long rowskip = 64 * (long)K;

  for (int k0 = 0; k0 < K; k0 += 32) {
    gload_lds16(gA + k0,           sA + (wid << 9));
    gload_lds16(gA + k0 + rowskip, sA + ((wid + 4) << 9));
    gload_lds16(gB + k0,           sB + (wid << 9));
    if (TN == 128)
      gload_lds16(gB + k0 + rowskip, sB + ((wid + 4) << 9));
    __syncthreads();
    bf16x8 af[4], bfr[NT];
    #pragma unroll
    for (int mt = 0; mt < 4; mt++)
      af[mt] = *(const bf16x8*)(sA + ((wm * 64 + mt * 16 + l16) << 5) + (quad << 3));
    #pragma unroll
    for (int nt = 0; nt < NT; nt++)
      bfr[nt] = *(const bf16x8*)(sB + ((wn * (TN / 2) + nt * 16 + l16) << 5) + (quad << 3));
    #pragma unroll
    for (int mt = 0; mt < 4; mt++)
      #pragma unroll
      for (int nt = 0; nt < NT; nt++)
        acc[mt][nt] = __builtin_amdgcn_mfma_f32_16x16x32_bf16(af[mt], bfr[nt], acc[mt][nt], 0, 0, 0);
    __syncthreads();
  }

  float bcol[NT];
  #pragma unroll
  for (int nt = 0; nt < NT; nt++) bcol[nt] = bias[tileN + wn * (TN / 2) + nt * 16 + l16];

  #pragma unroll
  for (int mt = 0; mt < 4; mt++) {
    #pragma unroll
    for (int r = 0; r < 4; r++) {
      long row = tileM + wm * 64 + mt * 16 + quad * 4 + r;
      if (MODE == 0) {
        __bf16* orow = outb + row * (long)N;
        #pragma unroll
        for (int nt = 0; nt < NT; nt++)
          orow[tileN + wn * (TN / 2) + nt * 16 + l16] = (__bf16)(acc[mt][nt][r] + bcol[nt]);
      } else if (MODE == 1) {
        if (row < MREAL) {
          int r32 = (int)row;
          int win = r32 / NTOK, t = r32 % NTOK;
          int rem = win % 100;
          int pr = (rem / 10) * 7 + t / 7;
          int pc = (rem % 10) * 7 + t % 7;
          if (pr < 64 && pc < 64) {
            long po = ((long)(win / 100) * 4096 + pr * 64 + pc) * DIM_;
            #pragma unroll
            for (int nt = 0; nt < NT; nt++) {
              long col = tileN + wn * (TN / 2) + nt * 16 + l16;
              outf[po + col] = res[po + col] + acc[mt][nt][r] + bcol[nt];
            }
          }
        }
      } else if (MODE == 2) {
        __bf16* orow = outb + row * (long)N;
        #pragma unroll
        for (int nt = 0; nt < NT; nt++) {
          float v = acc[mt][nt][r] + bcol[nt];
          orow[tileN + wn * (TN / 2) + nt * 16 + l16] = (__bf16)gelu_fast(v);
        }
      } else {
        float* orow = outf + row * (long)N;
        const float* rrow = res + row * (long)N;
        #pragma unroll
        for (int nt = 0; nt < NT; nt++) {
          long col = tileN + wn * (TN / 2) + nt * 16 + l16;
          orow[col] = acc[mt][nt][r] + bcol[nt] + rrow[col];
        }
      }
    }
  }
}

// ---------------------------------------------------------------------------
extern "C" void kernel_launch(void* const* d_in, const int* in_sizes, int n_in,
                              void* d_out, int out_size, void* d_ws, size_t ws_size,
                              hipStream_t stream) {
  const float* x       = (const float*)d_in[0];
  const float* ln1_g   = (const float*)d_in[1];
  const float* ln1_b   = (const float*)d_in[2];
  const float* qkv_w   = (const float*)d_in[3];
  const float* qkv_b   = (const float*)d_in[4];
  const float* proj_w  = (const float*)d_in[5];
  const float* proj_b  = (const float*)d_in[6];
  const float* attn_b  = (const float*)d_in[7];
  const float* conv_w  = (const float*)d_in[8];
  const float* bn_g    = (const float*)d_in[9];
  const float* bn_b    = (const float*)d_in[10];
  const float* bn_mean = (const float*)d_in[11];
  const float* bn_var  = (const float*)d_in[12];
  const float* ln2_g   = (const float*)d_in[13];
  const float* ln2_b   = (const float*)d_in[14];
  const float* fc1_w   = (const float*)d_in[15];
  const float* fc1_b   = (const float*)d_in[16];
  const float* fc2_w   = (const float*)d_in[17];
  const float* fc2_b   = (const float*)d_in[18];

  // workspace layout (aliasing; ~130 MB total):
  char* p = (char*)d_ws;
  __bf16* WQKV = (__bf16*)p;  p += 884736;     // 1152x384
  __bf16* WPROJ = (__bf16*)p; p += 294912;     // 384x384
  __bf16* WFC1 = (__bf16*)p;  p += 1179648;    // 1536x384
  __bf16* WFC2 = (__bf16*)p;  p += 1179648;    // 384x1536
  float*  WCONV = (float*)p;  p += 13824;      // 9x384
  char* region = p;           p += 75694080;
  float* X1 = (float*)p;      p += 25165824;
  float* X2 = (float*)p;      p += 25165824;
  __bf16* XN   = (__bf16*)region;                 // 19712x384 (dead after QKV gemm)
  float*  BM   = (float*)region;                  // 12x64x64 bias table (aliases XN)
  __bf16* QKVB = (__bf16*)(region + 15138816);    // 19712x1152
  __bf16* OBUF = (__bf16*)(region + 60555264);    // 19712x384
  __bf16* XLN2 = (__bf16*)region;                 // 16384x384  (aliases XN/BM, dead)
  __bf16* H1   = (__bf16*)(region + 15138816);    // 16384x1536 (aliases QKVB+OBUF, dead)
  float* OUT = (float*)d_out;

  transpose_cast<<<(442368 + 255) / 256, 256, 0, stream>>>(qkv_w, WQKV, DIM_, QKVD);
  transpose_cast<<<(147456 + 255) / 256, 256, 0, stream>>>(proj_w, WPROJ, DIM_, DIM_);
  transpose_cast<<<(589824 + 255) / 256, 256, 0, stream>>>(fc1_w, WFC1, DIM_, HIDD);
  transpose_cast<<<(589824 + 255) / 256, 256, 0, stream>>>(fc2_w, WFC2, HIDD, DIM_);
  convw_transpose<<<14, 256, 0, stream>>>(conv_w, WCONV);

  ln1_window<<<MPAD, 128, 0, stream>>>(x, ln1_g, ln1_b, XN);

  gemm_bf16<0, 128><<<dim3(MPAD / 128, QKVD / 128), 256, 0, stream>>>(
      XN, WQKV, qkv_b, DIM_, QKVD, nullptr, QKVB, nullptr);

  // XN dead now; BM aliases it.
  bias_expand<<<192, 256, 0, stream>>>(attn_b, BM);

  attn_mfma<<<NWIN * 12, 64, 0, stream>>>(QKVB, BM, OBUF);

  gemm_bf16<1, 64><<<dim3(MPAD / 128, DIM_ / 64), 256, 0, stream>>>(
      OBUF, WPROJ, proj_b, DIM_, DIM_, X1, nullptr, x);

  conv_bn_ln2<<<TOKENS / 4, 384, 0, stream>>>(X1, WCONV, bn_g, bn_b, bn_mean, bn_var,
                                              ln2_g, ln2_b, X2, XLN2);

  gemm_bf16<2, 128><<<dim3(TOKENS / 128, HIDD / 128), 256, 0, stream>>>(
      XLN2, WFC1, fc1_b, DIM_, HIDD, nullptr, H1, nullptr);

  gemm_bf16<3, 64><<<dim3(TOKENS / 128, DIM_ / 64), 256, 0, stream>>>(
      H1, WFC2, fc2_b, HIDD, DIM_, OUT, nullptr, X2);
}

// Round 6
// 296.690 us; speedup vs baseline: 1.4285x; 1.0972x over previous
//
#include <hip/hip_runtime.h>
#include <cstdint>

// ---------------------------------------------------------------------------
// TinyViT block on gfx950. Round 6:
//  - single fused prep kernel (4 weight transposes + conv-w + bias table +
//    LN1/window partition) -> 13 dispatches down to 7
//  - GEMM K-loop: BK=64 via dual BK=32 buffers (half the barrier pairs,
//    same conflict-free LDS layout), 32 MFMAs per barrier
//  - gelu via rcp intrinsic
// ---------------------------------------------------------------------------

typedef __bf16 bf16x8 __attribute__((ext_vector_type(8)));
typedef __bf16 bf16x4 __attribute__((ext_vector_type(4)));
typedef float  f32x4  __attribute__((ext_vector_type(4)));

#define DIM_    384
#define QKVD    1152
#define HIDD    1536
#define NTOK    49
#define NWIN    400
#define MPAD    19712     /* 154*128 */
#define MREAL   19600
#define TOKENS  16384     /* 4*4096 */
#define SCALE_  0.17677669529663689f
#define EPS_    1e-5f

// prep job block ranges (256 threads each)
#define B_LN1   9856      /* 19712 tokens, 2 per block        */
#define B_QKV   1728      /* 442368 elems                     */
#define B_PROJ  576       /* 147456                           */
#define B_FC1   2304      /* 589824                           */
#define B_FC2   2304      /* 589824                           */
#define B_CONV  14        /* 3456                             */
#define B_BIAS  192       /* 49152                            */
#define B_TOTAL (B_LN1 + B_QKV + B_PROJ + B_FC1 + B_FC2 + B_CONV + B_BIAS)

__device__ __forceinline__ void gload_lds16(const void* g, void* l) {
  __builtin_amdgcn_global_load_lds(
      (__attribute__((address_space(1))) void*)g,
      (__attribute__((address_space(3))) void*)l, 16, 0, 0);
}

// tanh-form GELU via sigmoid + fast rcp
__device__ __forceinline__ float gelu_fast(float v) {
  float t2 = v * (1.5957691216057308f + 0.07135481627f * v * v);
  return v * __builtin_amdgcn_rcpf(1.f + __expf(-t2));
}

// ---------------------------------------------------------------------------
// Fused prep: LN1+window partition, 4 weight transposes, conv-w transpose,
// attention bias table. One kernel, block-range dispatch, 256 threads.
// ---------------------------------------------------------------------------
__global__ __launch_bounds__(256) void prep_all(
    const float* __restrict__ x, const float* __restrict__ ln1_g,
    const float* __restrict__ ln1_b, __bf16* __restrict__ xn,
    const float* __restrict__ qkv_w,  __bf16* __restrict__ wqkv,
    const float* __restrict__ proj_w, __bf16* __restrict__ wproj,
    const float* __restrict__ fc1_w,  __bf16* __restrict__ wfc1,
    const float* __restrict__ fc2_w,  __bf16* __restrict__ wfc2,
    const float* __restrict__ conv_w, float* __restrict__ wconv,
    const float* __restrict__ attn_b, float* __restrict__ bm) {
  int b = blockIdx.x;
  int tid = threadIdx.x;

  if (b < B_LN1) {
    // ---- LN1 + window partition: 2 tokens per block, no early returns ----
    int sub = tid >> 7, tl = tid & 127;
    int t = b * 2 + sub;                       // 0..19711
    __bf16* orow = xn + (long)t * DIM_;
    int kind;                                  // 0=valid 1=bet-pad 2=zero-pad
    int bb = 0, r = 0, c = 0;
    if (t >= MREAL) kind = 2;
    else {
      int win = t / NTOK, tt = t % NTOK;
      bb = win / 100;
      int rem = win % 100;
      r = (rem / 10) * 7 + tt / 7;
      c = (rem % 10) * 7 + tt % 7;
      kind = (r >= 64 || c >= 64) ? 1 : 0;
    }
    float v0 = 0.f, v1 = 0.f, v2 = 0.f;
    if (kind == 0) {
      const float* xr = x + ((long)bb * 4096 + r * 64 + c) * DIM_;
      v0 = xr[tl]; v1 = xr[tl + 128]; v2 = xr[tl + 256];
    }
    float s = v0 + v1 + v2, s2 = v0 * v0 + v1 * v1 + v2 * v2;
    for (int off = 32; off; off >>= 1) { s += __shfl_down(s, off); s2 += __shfl_down(s2, off); }
    __shared__ float red[2][4];
    if ((tl & 63) == 0) { red[sub][tl >> 6] = s; red[sub][2 + (tl >> 6)] = s2; }
    __syncthreads();
    float S = red[sub][0] + red[sub][1], S2 = red[sub][2] + red[sub][3];
    float m  = S * (1.f / DIM_);
    float rs = rsqrtf(S2 * (1.f / DIM_) - m * m + EPS_);
    if (kind == 0) {
      orow[tl]       = (__bf16)((v0 - m) * rs * ln1_g[tl]       + ln1_b[tl]);
      orow[tl + 128] = (__bf16)((v1 - m) * rs * ln1_g[tl + 128] + ln1_b[tl + 128]);
      orow[tl + 256] = (__bf16)((v2 - m) * rs * ln1_g[tl + 256] + ln1_b[tl + 256]);
    } else if (kind == 1) {
      orow[tl]       = (__bf16)ln1_b[tl];
      orow[tl + 128] = (__bf16)ln1_b[tl + 128];
      orow[tl + 256] = (__bf16)ln1_b[tl + 256];
    } else {
      orow[tl] = (__bf16)0.f; orow[tl + 128] = (__bf16)0.f; orow[tl + 256] = (__bf16)0.f;
    }
    return;
  }
  b -= B_LN1;
  if (b < B_QKV) {               // qkv_w (384x1152) -> wqkv (1152x384)
    int id = b * 256 + tid;      // < 442368 exactly
    int k = id % DIM_; int n = id / DIM_;
    wqkv[id] = (__bf16)qkv_w[(long)k * QKVD + n];
    return;
  }
  b -= B_QKV;
  if (b < B_PROJ) {              // proj_w (384x384) -> wproj (384x384)^T
    int id = b * 256 + tid;
    int k = id % DIM_; int n = id / DIM_;
    wproj[id] = (__bf16)proj_w[(long)k * DIM_ + n];
    return;
  }
  b -= B_PROJ;
  if (b < B_FC1) {               // fc1_w (384x1536) -> wfc1 (1536x384)
    int id = b * 256 + tid;
    int k = id % DIM_; int n = id / DIM_;
    wfc1[id] = (__bf16)fc1_w[(long)k * HIDD + n];
    return;
  }
  b -= B_FC1;
  if (b < B_FC2) {               // fc2_w (1536x384) -> wfc2 (384x1536)
    int id = b * 256 + tid;
    int k = id % HIDD; int n = id / HIDD;
    wfc2[id] = (__bf16)fc2_w[(long)k * DIM_ + n];
    return;
  }
  b -= B_FC2;
  if (b < B_CONV) {              // conv_w [384][9] -> wconv [9][384]
    int id = b * 256 + tid;
    if (id < 3456) {
      int ch = id / 9, k = id % 9;
      wconv[k * DIM_ + ch] = conv_w[id];
    }
    return;
  }
  b -= B_CONV;
  {                              // bias table bm[12][64][64]
    int id = b * 256 + tid;      // < 49152
    int h = id >> 12, q = (id >> 6) & 63, kk = id & 63;
    float v;
    if (kk >= NTOK)      v = -1e30f;
    else if (q >= NTOK)  v = 0.f;
    else {
      int idx = abs(q / 7 - kk / 7) * 7 + abs(q % 7 - kk % 7);
      v = attn_b[h * NTOK + idx];
    }
    bm[id] = v;
  }
}

// ---------------------------------------------------------------------------
// Fused depthwise 3x3 conv + BN + LN2. Block = 4 pixels x 96 lanes (384 thr).
// ---------------------------------------------------------------------------
__global__ __launch_bounds__(384) void conv_bn_ln2(
    const float* __restrict__ x1, const float* __restrict__ wT,
    const float* __restrict__ bng, const float* __restrict__ bnb,
    const float* __restrict__ mean, const float* __restrict__ var,
    const float* __restrict__ g2, const float* __restrict__ b2,
    float* __restrict__ x2, __bf16* __restrict__ xln2) {
  int tid = threadIdx.x;
  int p = tid / 96, g = tid % 96;
  int pix = blockIdx.x * 4 + p;            // 0..16383
  int bb = pix >> 12, rc = pix & 4095;
  int r = rc >> 6, c = rc & 63;
  int ch = g << 2;

  f32x4 acc = (f32x4){0.f, 0.f, 0.f, 0.f};
  #pragma unroll
  for (int dr = -1; dr <= 1; dr++) {
    int rr = r + dr;
    if (rr < 0 || rr >= 64) continue;
    #pragma unroll
    for (int dc = -1; dc <= 1; dc++) {
      int cc = c + dc;
      if (cc < 0 || cc >= 64) continue;
      f32x4 xv = *(const f32x4*)(x1 + ((long)bb * 4096 + rr * 64 + cc) * DIM_ + ch);
      f32x4 wv = *(const f32x4*)(wT + ((dr + 1) * 3 + (dc + 1)) * DIM_ + ch);
      acc += xv * wv;
    }
  }

  f32x4 gv = *(const f32x4*)(bng + ch);
  f32x4 vv = *(const f32x4*)(var + ch);
  f32x4 mv = *(const f32x4*)(mean + ch);
  f32x4 bv = *(const f32x4*)(bnb + ch);
  f32x4 y;
  #pragma unroll
  for (int j = 0; j < 4; j++) {
    float sc = gv[j] * rsqrtf(vv[j] + EPS_);
    y[j] = acc[j] * sc + (bv[j] - mv[j] * sc);
  }
  *(f32x4*)(x2 + (long)pix * DIM_ + ch) = y;

  __shared__ float pS[4][96], pS2[4][96], mS[4], rS[4];
  pS[p][g]  = y[0] + y[1] + y[2] + y[3];
  pS2[p][g] = y[0] * y[0] + y[1] * y[1] + y[2] * y[2] + y[3] * y[3];
  __syncthreads();
  if (g < 32) {
    float a  = pS[p][g]  + pS[p][g + 32]  + pS[p][g + 64];
    float a2 = pS2[p][g] + pS2[p][g + 32] + pS2[p][g + 64];
    #pragma unroll
    for (int off = 1; off < 32; off <<= 1) {
      a  += __shfl_xor(a, off);
      a2 += __shfl_xor(a2, off);
    }
    if (g == 0) {
      float m = a * (1.f / DIM_);
      mS[p] = m;
      rS[p] = rsqrtf(a2 * (1.f / DIM_) - m * m + EPS_);
    }
  }
  __syncthreads();
  float m = mS[p], rs = rS[p];
  f32x4 gg = *(const f32x4*)(g2 + ch);
  f32x4 b2v = *(const f32x4*)(b2 + ch);
  bf16x4 ov;
  #pragma unroll
  for (int j = 0; j < 4; j++) ov[j] = (__bf16)((y[j] - m) * rs * gg[j] + b2v[j]);
  *(bf16x4*)(xln2 + (long)pix * DIM_ + ch) = ov;
}

// ---------------------------------------------------------------------------
// MFMA attention: one 64-thread block per (window, head). 4800 blocks.
// ---------------------------------------------------------------------------
__global__ __launch_bounds__(64) void attn_mfma(const __bf16* __restrict__ qkv,
                                                const float* __restrict__ bm,
                                                __bf16* __restrict__ o) {
  int blk = blockIdx.x;
  int win = blk / 12, h = blk % 12;
  int lane = threadIdx.x;
  int quad = lane >> 4, l16 = lane & 15;

  __shared__ __align__(16) __bf16 Vt[32][72];   // Vt[d][kk]
  __shared__ __align__(16) __bf16 P[64][72];    // P[q][kk]

  const __bf16* base = qkv + (long)win * NTOK * QKVD + h * 96;

  bf16x8 qf[4], kf[4];
  #pragma unroll
  for (int t = 0; t < 4; t++) {
    const __bf16* rp = base + (long)(t * 16 + l16) * QKVD + quad * 8;
    qf[t] = *(const bf16x8*)(rp);
    kf[t] = *(const bf16x8*)(rp + 32);
  }
  {
    const __bf16* vp = base + (long)lane * QKVD + 64;
    bf16x8 vv[4];
    #pragma unroll
    for (int i = 0; i < 4; i++) vv[i] = *(const bf16x8*)(vp + i * 8);
    #pragma unroll
    for (int i = 0; i < 4; i++)
      #pragma unroll
      for (int j = 0; j < 8; j++) Vt[i * 8 + j][lane] = vv[i][j];
  }

  f32x4 S[4][4];
  #pragma unroll
  for (int i = 0; i < 4; i++)
    #pragma unroll
    for (int j = 0; j < 4; j++) S[i][j] = (f32x4){0.f, 0.f, 0.f, 0.f};
  #pragma unroll
  for (int mt = 0; mt < 4; mt++)
    #pragma unroll
    for (int nt = 0; nt < 4; nt++)
      S[mt][nt] = __builtin_amdgcn_mfma_f32_16x16x32_bf16(qf[mt], kf[nt], S[mt][nt], 0, 0, 0);

  const float* bmh = bm + h * 4096;
  #pragma unroll
  for (int mt = 0; mt < 4; mt++)
    #pragma unroll
    for (int r = 0; r < 4; r++) {
      int q = mt * 16 + quad * 4 + r;
      #pragma unroll
      for (int nt = 0; nt < 4; nt++)
        S[mt][nt][r] = S[mt][nt][r] * SCALE_ + bmh[q * 64 + nt * 16 + l16];
    }

  #pragma unroll
  for (int mt = 0; mt < 4; mt++)
    #pragma unroll
    for (int r = 0; r < 4; r++) {
      float mx = fmaxf(fmaxf(S[mt][0][r], S[mt][1][r]), fmaxf(S[mt][2][r], S[mt][3][r]));
      #pragma unroll
      for (int off = 1; off < 16; off <<= 1) mx = fmaxf(mx, __shfl_xor(mx, off));
      float sum = 0.f;
      #pragma unroll
      for (int nt = 0; nt < 4; nt++) {
        float e = __expf(S[mt][nt][r] - mx);
        S[mt][nt][r] = e;
        sum += e;
      }
      #pragma unroll
      for (int off = 1; off < 16; off <<= 1) sum += __shfl_xor(sum, off);
      float inv = 1.f / sum;
      #pragma unroll
      for (int nt = 0; nt < 4; nt++) S[mt][nt][r] *= inv;
    }

  #pragma unroll
  for (int mt = 0; mt < 4; mt++)
    #pragma unroll
    for (int r = 0; r < 4; r++) {
      int q = mt * 16 + quad * 4 + r;
      #pragma unroll
      for (int nt = 0; nt < 4; nt++)
        P[q][nt * 16 + l16] = (__bf16)S[mt][nt][r];
    }
  __syncthreads();

  f32x4 O[4][2];
  #pragma unroll
  for (int i = 0; i < 4; i++)
    #pragma unroll
    for (int j = 0; j < 2; j++) O[i][j] = (f32x4){0.f, 0.f, 0.f, 0.f};
  #pragma unroll
  for (int kt = 0; kt < 2; kt++) {
    bf16x8 pf[4], vf[2];
    #pragma unroll
    for (int mt = 0; mt < 4; mt++)
      pf[mt] = *(const bf16x8*)(&P[mt * 16 + l16][kt * 32 + quad * 8]);
    #pragma unroll
    for (int nt = 0; nt < 2; nt++)
      vf[nt] = *(const bf16x8*)(&Vt[nt * 16 + l16][kt * 32 + quad * 8]);
    #pragma unroll
    for (int mt = 0; mt < 4; mt++)
      #pragma unroll
      for (int nt = 0; nt < 2; nt++)
        O[mt][nt] = __builtin_amdgcn_mfma_f32_16x16x32_bf16(pf[mt], vf[nt], O[mt][nt], 0, 0, 0);
  }

  __bf16* ob = o + (long)win * NTOK * DIM_ + h * 32;
  #pragma unroll
  for (int mt = 0; mt < 4; mt++)
    #pragma unroll
    for (int r = 0; r < 4; r++) {
      int q = mt * 16 + quad * 4 + r;
      if (q < NTOK) {
        #pragma unroll
        for (int nt = 0; nt < 2; nt++)
          ob[(long)q * DIM_ + nt * 16 + l16] = (__bf16)O[mt][nt][r];
      }
    }
}

// ---------------------------------------------------------------------------
// bf16 MFMA GEMM, C(MxN) = A(MxK) @ Bt(NxK)^T. Tile 128 x TN (TN=128 or 64),
// 4 waves (2x2), BK=64 via two BK=32 buffers (one barrier pair per 32 MFMAs),
// global_load_lds(16B) staging, fused epilogues.
// MODE 0: qkv   -> bf16 out = acc + bias
// MODE 1: proj  -> window-reverse scatter: X1 = x + acc + bias (valid pixels)
// MODE 2: fc1   -> bf16 out = gelu_fast(acc + bias)
// MODE 3: fc2   -> f32 out = acc + bias + res
// K must be a multiple of 64.
// ---------------------------------------------------------------------------
template <int MODE, int TN>
__global__ void __launch_bounds__(256)
gemm_bf16(const __bf16* __restrict__ A, const __bf16* __restrict__ Bt,
          const float* __restrict__ bias, int K, int N,
          float* __restrict__ outf, __bf16* __restrict__ outb,
          const float* __restrict__ res) {
  constexpr int NT = TN / 32;                 // acc col-tiles per wave
  __shared__ __align__(16) __bf16 sA[2][128 * 32];
  __shared__ __align__(16) __bf16 sB[2][TN * 32];
  int tid = threadIdx.x, lane = tid & 63, wid = tid >> 6;
  int wm = wid >> 1, wn = wid & 1;
  int quad = lane >> 4, l16 = lane & 15;
  long tileM = (long)blockIdx.x * 128;
  long tileN = (long)blockIdx.y * TN;

  f32x4 acc[4][NT];
  #pragma unroll
  for (int i = 0; i < 4; i++)
    #pragma unroll
    for (int j = 0; j < NT; j++) acc[i][j] = (f32x4){0.f, 0.f, 0.f, 0.f};

  int rr = wid * 16 + (lane >> 2);
  const __bf16* gA = A  + (tileM + rr) * (long)K + ((lane & 3) << 3);
  const __bf16* gB = Bt + (tileN + rr) * (long)K + ((lane & 3) << 3);
  const long rowskip = 64 * (long)K;

  for (int k0 = 0; k0 < K; k0 += 64) {
    #pragma unroll
    for (int h = 0; h < 2; h++) {
      const int ko = k0 + h * 32;
      gload_lds16(gA + ko,           &sA[h][wid << 9]);
      gload_lds16(gA + ko + rowskip, &sA[h][(wid + 4) << 9]);
      gload_lds16(gB + ko,           &sB[h][wid << 9]);
      if (TN == 128)
        gload_lds16(gB + ko + rowskip, &sB[h][(wid + 4) << 9]);
    }
    __syncthreads();
    #pragma unroll
    for (int h = 0; h < 2; h++) {
      bf16x8 af[4], bfr[NT];
      #pragma unroll
      for (int mt = 0; mt < 4; mt++)
        af[mt] = *(const bf16x8*)(&sA[h][((wm * 64 + mt * 16 + l16) << 5) + (quad << 3)]);
      #pragma unroll
      for (int nt = 0; nt < NT; nt++)
        bfr[nt] = *(const bf16x8*)(&sB[h][((wn * (TN / 2) + nt * 16 + l16) << 5) + (quad << 3)]);
      #pragma unroll
      for (int mt = 0; mt < 4; mt++)
        #pragma unroll
        for (int nt = 0; nt < NT; nt++)
          acc[mt][nt] = __builtin_amdgcn_mfma_f32_16x16x32_bf16(af[mt], bfr[nt], acc[mt][nt], 0, 0, 0);
    }
    __syncthreads();
  }

  float bcol[NT];
  #pragma unroll
  for (int nt = 0; nt < NT; nt++) bcol[nt] = bias[tileN + wn * (TN / 2) + nt * 16 + l16];

  #pragma unroll
  for (int mt = 0; mt < 4; mt++) {
    #pragma unroll
    for (int r = 0; r < 4; r++) {
      long row = tileM + wm * 64 + mt * 16 + quad * 4 + r;
      if (MODE == 0) {
        __bf16* orow = outb + row * (long)N;
        #pragma unroll
        for (int nt = 0; nt < NT; nt++)
          orow[tileN + wn * (TN / 2) + nt * 16 + l16] = (__bf16)(acc[mt][nt][r] + bcol[nt]);
      } else if (MODE == 1) {
        if (row < MREAL) {
          int r32 = (int)row;
          int win = r32 / NTOK, t = r32 % NTOK;
          int rem = win % 100;
          int pr = (rem / 10) * 7 + t / 7;
          int pc = (rem % 10) * 7 + t % 7;
          if (pr < 64 && pc < 64) {
            long po = ((long)(win / 100) * 4096 + pr * 64 + pc) * DIM_;
            #pragma unroll
            for (int nt = 0; nt < NT; nt++) {
              long col = tileN + wn * (TN / 2) + nt * 16 + l16;
              outf[po + col] = res[po + col] + acc[mt][nt][r] + bcol[nt];
            }
          }
        }
      } else if (MODE == 2) {
        __bf16* orow = outb + row * (long)N;
        #pragma unroll
        for (int nt = 0; nt < NT; nt++) {
          float v = acc[mt][nt][r] + bcol[nt];
          orow[tileN + wn * (TN / 2) + nt * 16 + l16] = (__bf16)gelu_fast(v);
        }
      } else {
        float* orow = outf + row * (long)N;
        const float* rrow = res + row * (long)N;
        #pragma unroll
        for (int nt = 0; nt < NT; nt++) {
          long col = tileN + wn * (TN / 2) + nt * 16 + l16;
          orow[col] = acc[mt][nt][r] + bcol[nt] + rrow[col];
        }
      }
    }
  }
}

// ---------------------------------------------------------------------------
extern "C" void kernel_launch(void* const* d_in, const int* in_sizes, int n_in,
                              void* d_out, int out_size, void* d_ws, size_t ws_size,
                              hipStream_t stream) {
  const float* x       = (const float*)d_in[0];
  const float* ln1_g   = (const float*)d_in[1];
  const float* ln1_b   = (const float*)d_in[2];
  const float* qkv_w   = (const float*)d_in[3];
  const float* qkv_b   = (const float*)d_in[4];
  const float* proj_w  = (const float*)d_in[5];
  const float* proj_b  = (const float*)d_in[6];
  const float* attn_b  = (const float*)d_in[7];
  const float* conv_w  = (const float*)d_in[8];
  const float* bn_g    = (const float*)d_in[9];
  const float* bn_b    = (const float*)d_in[10];
  const float* bn_mean = (const float*)d_in[11];
  const float* bn_var  = (const float*)d_in[12];
  const float* ln2_g   = (const float*)d_in[13];
  const float* ln2_b   = (const float*)d_in[14];
  const float* fc1_w   = (const float*)d_in[15];
  const float* fc1_b   = (const float*)d_in[16];
  const float* fc2_w   = (const float*)d_in[17];
  const float* fc2_b   = (const float*)d_in[18];

  // workspace layout (aliasing; ~130 MB total):
  char* p = (char*)d_ws;
  __bf16* WQKV = (__bf16*)p;  p += 884736;     // 1152x384
  __bf16* WPROJ = (__bf16*)p; p += 294912;     // 384x384
  __bf16* WFC1 = (__bf16*)p;  p += 1179648;    // 1536x384
  __bf16* WFC2 = (__bf16*)p;  p += 1179648;    // 384x1536
  float*  WCONV = (float*)p;  p += 13824;      // 9x384
  char* region = p;           p += 75694080;
  float* X1 = (float*)p;      p += 25165824;
  float* X2 = (float*)p;      p += 25165824;
  __bf16* XN   = (__bf16*)region;                 // 19712x384 (dead after QKV gemm)
  __bf16* QKVB = (__bf16*)(region + 15138816);    // 19712x1152
  __bf16* OBUF = (__bf16*)(region + 60555264);    // 19712x384
  __bf16* XLN2 = (__bf16*)region;                 // 16384x384  (aliases XN, dead)
  __bf16* H1   = (__bf16*)(region + 15138816);    // 16384x1536 (aliases QKVB+OBUF, dead)
  float*  BM   = X1;                              // 12x64x64 bias table; X1 not yet live
  float* OUT = (float*)d_out;

  prep_all<<<B_TOTAL, 256, 0, stream>>>(x, ln1_g, ln1_b, XN,
                                        qkv_w, WQKV, proj_w, WPROJ,
                                        fc1_w, WFC1, fc2_w, WFC2,
                                        conv_w, WCONV, attn_b, BM);

  gemm_bf16<0, 128><<<dim3(MPAD / 128, QKVD / 128), 256, 0, stream>>>(
      XN, WQKV, qkv_b, DIM_, QKVD, nullptr, QKVB, nullptr);

  attn_mfma<<<NWIN * 12, 64, 0, stream>>>(QKVB, BM, OBUF);

  gemm_bf16<1, 64><<<dim3(MPAD / 128, DIM_ / 64), 256, 0, stream>>>(
      OBUF, WPROJ, proj_b, DIM_, DIM_, X1, nullptr, x);

  conv_bn_ln2<<<TOKENS / 4, 384, 0, stream>>>(X1, WCONV, bn_g, bn_b, bn_mean, bn_var,
                                              ln2_g, ln2_b, X2, XLN2);

  gemm_bf16<2, 128><<<dim3(TOKENS / 128, HIDD / 128), 256, 0, stream>>>(
      XLN2, WFC1, fc1_b, DIM_, HIDD, nullptr, H1, nullptr);

  gemm_bf16<3, 64><<<dim3(TOKENS / 128, DIM_ / 64), 256, 0, stream>>>(
      H1, WFC2, fc2_b, HIDD, DIM_, OUT, nullptr, X2);
}